// Round 3
// baseline (338.809 us; speedup 1.0000x reference)
//
#include <hip/hip_runtime.h>
#include <hip/hip_bf16.h>

#define BB 4
#define SS 1024
#define NPTS 16384
#define DD 128
#define EPSF 1e-6f

// ws layout (float element offsets), total ~2.99 MB
#define OFF_CQ     0        // 128  colsum(Wq)
#define OFF_CK     128      // 128  colsum(Wk)
#define OFF_W2S    256      // 128  colsum(W2)
#define OFF_SCL    384      // 8    [0]=sum(bq) [1]=sum(bk) [2]=sum(b2)
#define OFF_COL    448      // 64   colsum of attn over S, per (b,j)
#define OFF_QSUM   512      // 4096
#define OFF_KSUM   4608     // 65536
#define OFF_IDX    70144    // 65536 (int)
#define OFF_ATTN   135680   // 65536
#define OFF_ASUM   201216   // 4096
#define OFF_G      205312   // 524288 (k_gather output; during k_knn reused as kp4: (x,y,z,kk) per point, 262144 floats)
#define OFF_WVT    729600   // 16384 (Wv transposed)

__device__ __forceinline__ unsigned long long shflxor_u64(unsigned long long v, int m) {
  unsigned int lo = (unsigned int)(v & 0xffffffffull);
  unsigned int hi = (unsigned int)(v >> 32);
  lo = (unsigned int)__shfl_xor((int)lo, m, 64);
  hi = (unsigned int)__shfl_xor((int)hi, m, 64);
  return ((unsigned long long)hi << 32) | (unsigned long long)lo;
}

__device__ __forceinline__ unsigned long long u64min(unsigned long long a, unsigned long long b) {
  return a < b ? a : b;
}

__device__ __forceinline__ unsigned long long wavemin_u64(unsigned long long v) {
#pragma unroll
  for (int m = 1; m <= 32; m <<= 1) v = u64min(v, shflxor_u64(v, m));
  return v;
}

// ---------- K1: column sums, bias sums, Wv transpose, zero colsum ----------
// 128 blocks x 128 threads: block j = output column j
__global__ __launch_bounds__(128) void k_prep(const float* __restrict__ Wq, const float* __restrict__ bq,
                       const float* __restrict__ Wk, const float* __restrict__ bk,
                       const float* __restrict__ Wv, const float* __restrict__ W2,
                       const float* __restrict__ b2, float* __restrict__ ws) {
  const int j = (int)blockIdx.x;
  const int t = threadIdx.x;
  __shared__ float pr[6];
  __shared__ float pb[6];
  float s0 = Wq[t * DD + j], s1 = Wk[t * DD + j], s2 = W2[t * DD + j];
#pragma unroll
  for (int m = 1; m <= 32; m <<= 1) {
    s0 += __shfl_xor(s0, m, 64);
    s1 += __shfl_xor(s1, m, 64);
    s2 += __shfl_xor(s2, m, 64);
  }
  if ((t & 63) == 0) { const int wv = t >> 6; pr[wv*3+0]=s0; pr[wv*3+1]=s1; pr[wv*3+2]=s2; }
  __syncthreads();
  if (t == 0) {
    ws[OFF_CQ + j]  = pr[0] + pr[3];
    ws[OFF_CK + j]  = pr[1] + pr[4];
    ws[OFF_W2S + j] = pr[2] + pr[5];
  }
  ws[OFF_WVT + j * DD + t] = Wv[t * DD + j];
  if (j == 1 && t < 64) ws[OFF_COL + t] = 0.f;
  if (j == 0) {
    float a0 = bq[t], a1 = bk[t], a2 = b2[t];
#pragma unroll
    for (int m = 1; m <= 32; m <<= 1) {
      a0 += __shfl_xor(a0, m, 64);
      a1 += __shfl_xor(a1, m, 64);
      a2 += __shfl_xor(a2, m, 64);
    }
    if ((t & 63) == 0) { const int wv = t >> 6; pb[wv*3+0]=a0; pb[wv*3+1]=a1; pb[wv*3+2]=a2; }
    __syncthreads();
    if (t == 0) {
      ws[OFF_SCL + 0] = pb[0] + pb[3];
      ws[OFF_SCL + 1] = pb[1] + pb[4];
      ws[OFF_SCL + 2] = pb[2] + pb[5];
    }
  }
}

// ---------- K2: ksum/qsum row sums + pack kp4 = (x,y,z,kk) ----------
__global__ __launch_bounds__(256) void k_rowsums(const float* __restrict__ kf,
                                                 const float* __restrict__ qf,
                                                 const float* __restrict__ kpos,
                                                 float* __restrict__ ws) {
  const int tid = threadIdx.x;
  // pack kp4: first 65536 global threads each pack one point.
  // kk arithmetic identical to the previous inline version: ((x*x + y*y) + z*z)
  const int pid = (int)blockIdx.x * 256 + tid;
  if (pid < BB * NPTS) {
    const float x = kpos[pid * 3 + 0], y = kpos[pid * 3 + 1], z = kpos[pid * 3 + 2];
    const float kk = __fadd_rn(__fadd_rn(__fmul_rn(x, x), __fmul_rn(y, y)), __fmul_rn(z, z));
    ((float4*)(ws + OFF_G))[pid] = make_float4(x, y, z, kk);
  }
  const int g = ((int)blockIdx.x * 256 + tid) >> 4;
  const int gl = tid & 15;
  const int ngroups = (int)gridDim.x * 16;
  const float bqs = ws[OFF_SCL + 0], bks = ws[OFF_SCL + 1];
  const int total = BB * NPTS + BB * SS;
  for (int row = g; row < total; row += ngroups) {
    const float* x;
    const float* c;
    if (row < BB * NPTS) { x = kf + (size_t)row * DD; c = ws + OFF_CK; }
    else                 { x = qf + (size_t)(row - BB * NPTS) * DD; c = ws + OFF_CQ; }
    float4 a  = *(const float4*)(x + gl * 4);
    float4 b  = *(const float4*)(x + 64 + gl * 4);
    float4 ca = *(const float4*)(c + gl * 4);
    float4 cb = *(const float4*)(c + 64 + gl * 4);
    float s = a.x * ca.x + a.y * ca.y + a.z * ca.z + a.w * ca.w
            + b.x * cb.x + b.y * cb.y + b.z * cb.z + b.w * cb.w;
    s += __shfl_xor(s, 1, 64);
    s += __shfl_xor(s, 2, 64);
    s += __shfl_xor(s, 4, 64);
    s += __shfl_xor(s, 8, 64);
    if (gl == 0) {
      if (row < BB * NPTS) ws[OFF_KSUM + row] = s + bks;
      else                 ws[OFF_QSUM + (row - BB * NPTS)] = s + bqs;
    }
  }
}

// ---------- K3: fused KNN + pe-sum + scores + softmax + colsum atomics ----------
// Q=4 queries per WAVE, LDS-STAGED point scan (fix for R2's serialized-latency
// regression: at 1 wave/SIMD the compiler would not pipeline global loads, so
// each scan iter paid full L2/L3 latency). Points are staged through a
// double-buffered LDS chunk (2048 pts = 32 KB x2) with reg-staged prefetch:
// issue next chunk's 8x global_load_dwordx4 BEFORE computing current chunk
// from LDS, commit via ds_write AFTER the post-compute barrier (T14 pattern).
// Selection logic (pass1 min / cutoff / pass2 compact / merge) is bit-identical
// to the previously verified version; point->lane map p = c*2048 + it*64 + l
// equals the old p = t*64 + l.
// d2 matches numpy's einsum C kernel bit-for-bit (verified R8):
//   dot: DESCENDING no-FMA; qq/kk: plain squares, ASCENDING add;
//   d2 = (qq - 2*dot) + kk. kk precomputed in k_rowsums with same ops.
__global__ __launch_bounds__(256, 1) void k_knn(const float* __restrict__ qpos,
                                                const float* __restrict__ kpos,
                                                const float* __restrict__ W1,
                                                const float* __restrict__ b1,
                                                float* __restrict__ ws) {
  __shared__ float4 pts[2][2048];                 // 64 KB double buffer
  __shared__ unsigned long long cbuf[4][4][256];  // [wave][query][slot] 32 KB
  __shared__ int sidx[4][4][16];                  // [wave][query][rank]
  const int tid = threadIdx.x;
  const int w = tid >> 6, l = tid & 63;
  const int qbase = ((int)blockIdx.x * 4 + w) * 4;  // 4 queries per wave
  const int b = qbase >> 10;                        // same batch for all 4

  const float4* kp4 = (const float4*)(ws + OFF_G) + (size_t)b * NPTS;

  float qx[4], qy[4], qz[4], qq[4];
#pragma unroll
  for (int i = 0; i < 4; ++i) {
    const float* qp = qpos + (size_t)(qbase + i) * 3;
    qx[i] = qp[0]; qy[i] = qp[1]; qz[i] = qp[2];
    qq[i] = __fadd_rn(__fadd_rn(__fmul_rn(qx[i], qx[i]), __fmul_rn(qy[i], qy[i])), __fmul_rn(qz[i], qz[i]));
  }

  float4 stg[8];

  // ---- prologue: stage chunk 0 ----
  {
    const float4* src = kp4 + tid;
#pragma unroll
    for (int i = 0; i < 8; ++i) stg[i] = src[i * 256];
    float4* dst = &pts[0][tid];
#pragma unroll
    for (int i = 0; i < 8; ++i) dst[i * 256] = stg[i];
  }
  __syncthreads();

  // ---- pass 1: per-lane min of exact d2, 4 queries per LDS point read ----
  float mn0 = 3.4e38f, mn1 = 3.4e38f, mn2 = 3.4e38f, mn3 = 3.4e38f;
  for (int c = 0; c < 8; ++c) {
    if (c < 7) {
      const float4* src = kp4 + (c + 1) * 2048 + tid;
#pragma unroll
      for (int i = 0; i < 8; ++i) stg[i] = src[i * 256];
    }
    const float4* lp = &pts[c & 1][l];
#pragma unroll 4
    for (int it = 0; it < 32; ++it) {
      const float4 cc = lp[it * 64];
      const float dot0 = __fadd_rn(__fadd_rn(__fmul_rn(qz[0], cc.z), __fmul_rn(qy[0], cc.y)), __fmul_rn(qx[0], cc.x));
      const float dot1 = __fadd_rn(__fadd_rn(__fmul_rn(qz[1], cc.z), __fmul_rn(qy[1], cc.y)), __fmul_rn(qx[1], cc.x));
      const float dot2 = __fadd_rn(__fadd_rn(__fmul_rn(qz[2], cc.z), __fmul_rn(qy[2], cc.y)), __fmul_rn(qx[2], cc.x));
      const float dot3 = __fadd_rn(__fadd_rn(__fmul_rn(qz[3], cc.z), __fmul_rn(qy[3], cc.y)), __fmul_rn(qx[3], cc.x));
      const float d20 = __fadd_rn(__fsub_rn(qq[0], __fmul_rn(2.0f, dot0)), cc.w);
      const float d21 = __fadd_rn(__fsub_rn(qq[1], __fmul_rn(2.0f, dot1)), cc.w);
      const float d22 = __fadd_rn(__fsub_rn(qq[2], __fmul_rn(2.0f, dot2)), cc.w);
      const float d23 = __fadd_rn(__fsub_rn(qq[3], __fmul_rn(2.0f, dot3)), cc.w);
      mn0 = fminf(mn0, d20);
      mn1 = fminf(mn1, d21);
      mn2 = fminf(mn2, d22);
      mn3 = fminf(mn3, d23);
    }
    __syncthreads();
    if (c < 7) {
      float4* dst = &pts[(c + 1) & 1][tid];
#pragma unroll
      for (int i = 0; i < 8; ++i) dst[i * 256] = stg[i];
      __syncthreads();
    }
  }

  // ---- cutoff per query: 16th smallest distinct lane-min (interleaved) ----
  float v0 = mn0, v1 = mn1, v2 = mn2, v3 = mn3;
  float cut0 = 0.f, cut1 = 0.f, cut2 = 0.f, cut3 = 0.f;
  for (int r = 0; r < 16; ++r) {
    float m0 = v0, m1 = v1, m2 = v2, m3 = v3;
#pragma unroll
    for (int s = 1; s <= 32; s <<= 1) {
      m0 = fminf(m0, __shfl_xor(m0, s, 64));
      m1 = fminf(m1, __shfl_xor(m1, s, 64));
      m2 = fminf(m2, __shfl_xor(m2, s, 64));
      m3 = fminf(m3, __shfl_xor(m3, s, 64));
    }
    cut0 = m0; cut1 = m1; cut2 = m2; cut3 = m3;
    if (v0 == m0) v0 = 3.4e38f;
    if (v1 == m1) v1 = 3.4e38f;
    if (v2 == m2) v2 = 3.4e38f;
    if (v3 == m3) v3 = 3.4e38f;
  }

  // ---- pass 2: ballot-compact candidates per query into LDS ----
  int cnt0 = 0, cnt1 = 0, cnt2 = 0, cnt3 = 0;
#define PASS2_Q(i, d2v, cutv, cntv)                                            \
  {                                                                            \
    const bool pred = (d2v <= cutv);                                           \
    const unsigned long long mask = __ballot(pred);                            \
    if (pred) {                                                                \
      const int off = __builtin_amdgcn_mbcnt_hi((unsigned int)(mask >> 32),    \
                      __builtin_amdgcn_mbcnt_lo((unsigned int)mask, 0));       \
      unsigned int u = __float_as_uint(d2v);                                   \
      u ^= (unsigned int)((int)u >> 31) | 0x80000000u;                         \
      const int pos = cntv + off;                                              \
      if (pos < 256) cbuf[w][i][pos] = ((unsigned long long)u << 32) | (unsigned int)p; \
    }                                                                          \
    cntv += (int)__popcll(mask);                                               \
  }
  // restage chunk 0 (pts[0] free: all waves synced after pass-1 tail)
  {
    const float4* src = kp4 + tid;
#pragma unroll
    for (int i = 0; i < 8; ++i) stg[i] = src[i * 256];
    float4* dst = &pts[0][tid];
#pragma unroll
    for (int i = 0; i < 8; ++i) dst[i * 256] = stg[i];
  }
  __syncthreads();
  for (int c = 0; c < 8; ++c) {
    if (c < 7) {
      const float4* src = kp4 + (c + 1) * 2048 + tid;
#pragma unroll
      for (int i = 0; i < 8; ++i) stg[i] = src[i * 256];
    }
    const float4* lp = &pts[c & 1][l];
    int p = c * 2048 + l;
#pragma unroll 2
    for (int it = 0; it < 32; ++it) {
      const float4 cc = lp[it * 64];
      const float dot0 = __fadd_rn(__fadd_rn(__fmul_rn(qz[0], cc.z), __fmul_rn(qy[0], cc.y)), __fmul_rn(qx[0], cc.x));
      const float dot1 = __fadd_rn(__fadd_rn(__fmul_rn(qz[1], cc.z), __fmul_rn(qy[1], cc.y)), __fmul_rn(qx[1], cc.x));
      const float dot2 = __fadd_rn(__fadd_rn(__fmul_rn(qz[2], cc.z), __fmul_rn(qy[2], cc.y)), __fmul_rn(qx[2], cc.x));
      const float dot3 = __fadd_rn(__fadd_rn(__fmul_rn(qz[3], cc.z), __fmul_rn(qy[3], cc.y)), __fmul_rn(qx[3], cc.x));
      const float d20 = __fadd_rn(__fsub_rn(qq[0], __fmul_rn(2.0f, dot0)), cc.w);
      const float d21 = __fadd_rn(__fsub_rn(qq[1], __fmul_rn(2.0f, dot1)), cc.w);
      const float d22 = __fadd_rn(__fsub_rn(qq[2], __fmul_rn(2.0f, dot2)), cc.w);
      const float d23 = __fadd_rn(__fsub_rn(qq[3], __fmul_rn(2.0f, dot3)), cc.w);
      PASS2_Q(0, d20, cut0, cnt0)
      PASS2_Q(1, d21, cut1, cnt1)
      PASS2_Q(2, d22, cut2, cnt2)
      PASS2_Q(3, d23, cut3, cnt3)
      p += 64;
    }
    __syncthreads();
    if (c < 7) {
      float4* dst = &pts[(c + 1) & 1][tid];
#pragma unroll
      for (int i = 0; i < 8; ++i) dst[i * 256] = stg[i];
      __syncthreads();
    }
  }
#undef PASS2_Q
  int cnts[4];
  cnts[0] = cnt0 > 256 ? 256 : cnt0;
  cnts[1] = cnt1 > 256 ? 256 : cnt1;
  cnts[2] = cnt2 > 256 ? 256 : cnt2;
  cnts[3] = cnt3 > 256 ? 256 : cnt3;

  // ---- merge per query: 16 rounds of wave-min, mark-and-rescan ----
#pragma unroll
  for (int qi = 0; qi < 4; ++qi) {
    const int cnt = cnts[qi];
    unsigned long long cand[4];
#pragma unroll
    for (int i = 0; i < 4; ++i) {
      const int pos = l + i * 64;
      cand[i] = (pos < cnt) ? cbuf[w][qi][pos] : ~0ull;
    }
    unsigned long long lmin = cand[0]; int lpos = 0;
#pragma unroll
    for (int i = 1; i < 4; ++i) { if (cand[i] < lmin) { lmin = cand[i]; lpos = i; } }
    unsigned long long sel64 = 0;
    for (int r = 0; r < 16; ++r) {
      const unsigned long long m = wavemin_u64(lmin);
      if (l == r) sel64 = m;
      if (lmin == m) {
#pragma unroll
        for (int i = 0; i < 4; ++i) cand[i] = (lpos == i) ? ~0ull : cand[i];
        lmin = cand[0]; lpos = 0;
#pragma unroll
        for (int i = 1; i < 4; ++i) { if (cand[i] < lmin) { lmin = cand[i]; lpos = i; } }
      }
    }
    const int myidx = (int)(sel64 & 0xffffffffull);
    if (l < 16) {
      ((int*)(ws + OFF_IDX))[(qbase + qi) * 16 + l] = myidx;
      sidx[w][qi][l] = myidx;
    }
  }
  __syncthreads();

  // ---- scores: group g = l>>4 owns query g, lane j = l&15 owns neighbor j ----
  const int g = l >> 4;
  const int j = l & 15;
  const int q = qbase + g;
  const int pj = sidx[w][g][j];
  const float4 cj = kp4[pj];
  const float gx = (g == 0) ? qx[0] : ((g == 1) ? qx[1] : ((g == 2) ? qx[2] : qx[3]));
  const float gy = (g == 0) ? qy[0] : ((g == 1) ? qy[1] : ((g == 2) ? qy[2] : qy[3]));
  const float gz = (g == 0) ? qz[0] : ((g == 1) ? qz[1] : ((g == 2) ? qz[2] : qz[3]));
  const float rx = gx - cj.x;
  const float ry = gy - cj.y;
  const float rz = gz - cj.z;
  float pe = 0.f;
#pragma unroll 4
  for (int i = 0; i < 128; ++i) {
    float hh = fmaf(rx, W1[i * 3 + 0], fmaf(ry, W1[i * 3 + 1], fmaf(rz, W1[i * 3 + 2], b1[i])));
    hh = fmaxf(hh, 0.f);
    pe = fmaf(hh, ws[OFF_W2S + i], pe);
  }
  float score = ws[OFF_QSUM + q] - ws[OFF_KSUM + b * NPTS + pj] + pe + ws[OFF_SCL + 2];
  float mx = score;
  mx = fmaxf(mx, __shfl_xor(mx, 1, 64));
  mx = fmaxf(mx, __shfl_xor(mx, 2, 64));
  mx = fmaxf(mx, __shfl_xor(mx, 4, 64));
  mx = fmaxf(mx, __shfl_xor(mx, 8, 64));
  const float e = expf(score - mx);
  float se = e;
  se += __shfl_xor(se, 1, 64);
  se += __shfl_xor(se, 2, 64);
  se += __shfl_xor(se, 4, 64);
  se += __shfl_xor(se, 8, 64);
  const float attn = e / se;
  ws[OFF_ATTN + q * 16 + j] = attn;
  atomicAdd(&ws[OFF_COL + b * 16 + j], attn);
}

// ---------- K4: normalize attn, gather-weight k_feat rows -> g, asum ----------
__global__ __launch_bounds__(256) void k_gather(const float* __restrict__ kf,
                                                float* __restrict__ ws) {
  const int tid = threadIdx.x;
  const int w = tid >> 6, l = tid & 63;
  const int q = (int)blockIdx.x * 4 + w;
  const int b = q >> 10;
  float a = 0.f;
  int pidx = 0;
  if (l < 16) {
    a = ws[OFF_ATTN + q * 16 + l] / (ws[OFF_COL + b * 16 + l] + EPSF);
    pidx = ((const int*)(ws + OFF_IDX))[q * 16 + l];
  }
  float asum = a;
  asum += __shfl_xor(asum, 1, 64);
  asum += __shfl_xor(asum, 2, 64);
  asum += __shfl_xor(asum, 4, 64);
  asum += __shfl_xor(asum, 8, 64);
  if (l == 0) ws[OFF_ASUM + q] = asum;
  const float* kb = kf + (size_t)b * NPTS * DD;
  float acc0 = 0.f, acc1 = 0.f;
#pragma unroll
  for (int jj = 0; jj < 16; ++jj) {
    const float aj = __shfl(a, jj, 64);
    const int pj = __shfl(pidx, jj, 64);
    const float* row = kb + (size_t)pj * DD;
    acc0 = fmaf(aj, row[l], acc0);
    acc1 = fmaf(aj, row[64 + l], acc1);
  }
  ws[OFF_G + (size_t)q * DD + l] = acc0;
  ws[OFF_G + (size_t)q * DD + 64 + l] = acc1;
}

// ---------- K5: out = g @ Wv^T + asum * bv ----------
__global__ __launch_bounds__(256) void k_out(const float* __restrict__ bv,
                                             const float* __restrict__ ws,
                                             float* __restrict__ out) {
  __shared__ float xg[16 * 128];
  __shared__ float as_s[16];
  const int tid = threadIdx.x;
  const int rbase = (int)blockIdx.x * 16;
  for (int e = tid; e < 16 * 128; e += 256) xg[e] = ws[OFF_G + (size_t)rbase * DD + e];
  if (tid < 16) as_s[tid] = ws[OFF_ASUM + rbase + tid];
  __syncthreads();
  const int o = tid & 127, rg = tid >> 7;
  const float bvo = bv[o];
  float acc[8];
#pragma unroll
  for (int r = 0; r < 8; ++r) acc[r] = as_s[rg * 8 + r] * bvo;
  for (int i = 0; i < DD; ++i) {
    const float wv = ws[OFF_WVT + i * DD + o];
#pragma unroll
    for (int r = 0; r < 8; ++r) acc[r] = fmaf(wv, xg[(rg * 8 + r) * 128 + i], acc[r]);
  }
#pragma unroll
  for (int r = 0; r < 8; ++r) out[(size_t)(rbase + rg * 8 + r) * DD + o] = acc[r];
}

extern "C" void kernel_launch(void* const* d_in, const int* in_sizes, int n_in,
                              void* d_out, int out_size, void* d_ws, size_t ws_size,
                              hipStream_t stream) {
  const float* qf   = (const float*)d_in[0];
  const float* kf   = (const float*)d_in[1];
  const float* qpos = (const float*)d_in[2];
  const float* kpos = (const float*)d_in[3];
  const float* Wq   = (const float*)d_in[4];
  const float* bq   = (const float*)d_in[5];
  const float* Wk   = (const float*)d_in[6];
  const float* bk   = (const float*)d_in[7];
  const float* Wv   = (const float*)d_in[8];
  const float* bv   = (const float*)d_in[9];
  const float* W1   = (const float*)d_in[10];
  const float* b1   = (const float*)d_in[11];
  const float* W2   = (const float*)d_in[12];
  const float* b2   = (const float*)d_in[13];
  float* ws  = (float*)d_ws;
  float* out = (float*)d_out;

  k_prep<<<128, 128, 0, stream>>>(Wq, bq, Wk, bk, Wv, W2, b2, ws);
  k_rowsums<<<1024, 256, 0, stream>>>(kf, qf, kpos, ws);
  k_knn<<<256, 256, 0, stream>>>(qpos, kpos, W1, b1, ws);
  k_gather<<<1024, 256, 0, stream>>>(kf, ws);
  k_out<<<256, 256, 0, stream>>>(bv, ws, out);
}

// Round 4
// 219.217 us; speedup vs baseline: 1.5455x; 1.5455x over previous
//
#include <hip/hip_runtime.h>
#include <hip/hip_bf16.h>

#define BB 4
#define SS 1024
#define NPTS 16384
#define DD 128
#define EPSF 1e-6f

// ws layout (float element offsets), total ~2.99 MB
#define OFF_CQ     0        // 128  colsum(Wq)
#define OFF_CK     128      // 128  colsum(Wk)
#define OFF_W2S    256      // 128  colsum(W2)
#define OFF_SCL    384      // 8    [0]=sum(bq) [1]=sum(bk) [2]=sum(b2)
#define OFF_COL    448      // 64   colsum of attn over S, per (b,j)
#define OFF_QSUM   512      // 4096
#define OFF_KSUM   4608     // 65536
#define OFF_IDX    70144    // 65536 (int)
#define OFF_ATTN   135680   // 65536
#define OFF_ASUM   201216   // 4096
#define OFF_G      205312   // 524288 (k_gather output; during k_knn reused as kp4: (x,y,z,kk) per point, 262144 floats)
#define OFF_WVT    729600   // 16384 (Wv transposed)

__device__ __forceinline__ unsigned long long shflxor_u64(unsigned long long v, int m) {
  unsigned int lo = (unsigned int)(v & 0xffffffffull);
  unsigned int hi = (unsigned int)(v >> 32);
  lo = (unsigned int)__shfl_xor((int)lo, m, 64);
  hi = (unsigned int)__shfl_xor((int)hi, m, 64);
  return ((unsigned long long)hi << 32) | (unsigned long long)lo;
}

__device__ __forceinline__ unsigned long long u64min(unsigned long long a, unsigned long long b) {
  return a < b ? a : b;
}

__device__ __forceinline__ unsigned long long wavemin_u64(unsigned long long v) {
#pragma unroll
  for (int m = 1; m <= 32; m <<= 1) v = u64min(v, shflxor_u64(v, m));
  return v;
}

// ---------- K1: column sums, bias sums, Wv transpose, zero colsum ----------
// 128 blocks x 128 threads: block j = output column j
__global__ __launch_bounds__(128) void k_prep(const float* __restrict__ Wq, const float* __restrict__ bq,
                       const float* __restrict__ Wk, const float* __restrict__ bk,
                       const float* __restrict__ Wv, const float* __restrict__ W2,
                       const float* __restrict__ b2, float* __restrict__ ws) {
  const int j = (int)blockIdx.x;
  const int t = threadIdx.x;
  __shared__ float pr[6];
  __shared__ float pb[6];
  float s0 = Wq[t * DD + j], s1 = Wk[t * DD + j], s2 = W2[t * DD + j];
#pragma unroll
  for (int m = 1; m <= 32; m <<= 1) {
    s0 += __shfl_xor(s0, m, 64);
    s1 += __shfl_xor(s1, m, 64);
    s2 += __shfl_xor(s2, m, 64);
  }
  if ((t & 63) == 0) { const int wv = t >> 6; pr[wv*3+0]=s0; pr[wv*3+1]=s1; pr[wv*3+2]=s2; }
  __syncthreads();
  if (t == 0) {
    ws[OFF_CQ + j]  = pr[0] + pr[3];
    ws[OFF_CK + j]  = pr[1] + pr[4];
    ws[OFF_W2S + j] = pr[2] + pr[5];
  }
  ws[OFF_WVT + j * DD + t] = Wv[t * DD + j];
  if (j == 1 && t < 64) ws[OFF_COL + t] = 0.f;
  if (j == 0) {
    float a0 = bq[t], a1 = bk[t], a2 = b2[t];
#pragma unroll
    for (int m = 1; m <= 32; m <<= 1) {
      a0 += __shfl_xor(a0, m, 64);
      a1 += __shfl_xor(a1, m, 64);
      a2 += __shfl_xor(a2, m, 64);
    }
    if ((t & 63) == 0) { const int wv = t >> 6; pb[wv*3+0]=a0; pb[wv*3+1]=a1; pb[wv*3+2]=a2; }
    __syncthreads();
    if (t == 0) {
      ws[OFF_SCL + 0] = pb[0] + pb[3];
      ws[OFF_SCL + 1] = pb[1] + pb[4];
      ws[OFF_SCL + 2] = pb[2] + pb[5];
    }
  }
}

// ---------- K2: ksum/qsum row sums + pack kp4 = (x,y,z,kk) ----------
__global__ __launch_bounds__(256) void k_rowsums(const float* __restrict__ kf,
                                                 const float* __restrict__ qf,
                                                 const float* __restrict__ kpos,
                                                 float* __restrict__ ws) {
  const int tid = threadIdx.x;
  // pack kp4: first 65536 global threads each pack one point.
  // kk arithmetic identical to the original inline version: ((x*x + y*y) + z*z)
  const int pid = (int)blockIdx.x * 256 + tid;
  if (pid < BB * NPTS) {
    const float x = kpos[pid * 3 + 0], y = kpos[pid * 3 + 1], z = kpos[pid * 3 + 2];
    const float kk = __fadd_rn(__fadd_rn(__fmul_rn(x, x), __fmul_rn(y, y)), __fmul_rn(z, z));
    ((float4*)(ws + OFF_G))[pid] = make_float4(x, y, z, kk);
  }
  const int g = ((int)blockIdx.x * 256 + tid) >> 4;
  const int gl = tid & 15;
  const int ngroups = (int)gridDim.x * 16;
  const float bqs = ws[OFF_SCL + 0], bks = ws[OFF_SCL + 1];
  const int total = BB * NPTS + BB * SS;
  for (int row = g; row < total; row += ngroups) {
    const float* x;
    const float* c;
    if (row < BB * NPTS) { x = kf + (size_t)row * DD; c = ws + OFF_CK; }
    else                 { x = qf + (size_t)(row - BB * NPTS) * DD; c = ws + OFF_CQ; }
    float4 a  = *(const float4*)(x + gl * 4);
    float4 b  = *(const float4*)(x + 64 + gl * 4);
    float4 ca = *(const float4*)(c + gl * 4);
    float4 cb = *(const float4*)(c + 64 + gl * 4);
    float s = a.x * ca.x + a.y * ca.y + a.z * ca.z + a.w * ca.w
            + b.x * cb.x + b.y * cb.y + b.z * cb.z + b.w * cb.w;
    s += __shfl_xor(s, 1, 64);
    s += __shfl_xor(s, 2, 64);
    s += __shfl_xor(s, 4, 64);
    s += __shfl_xor(s, 8, 64);
    if (gl == 0) {
      if (row < BB * NPTS) ws[OFF_KSUM + row] = s + bks;
      else                 ws[OFF_QSUM + (row - BB * NPTS)] = s + bqs;
    }
  }
}

// ---------- K3: fused KNN + pe-sum + scores + softmax + colsum atomics ----------
// R4: back to the R1 structure that measured best (1024 blocks, wave = 1 query,
// 16 waves/CU so TLP hides load latency) with two fixes for its measured costs:
//   (a) packed kp4 float4 loads (1 load instr/point instead of 3; kk precomputed
//       with identical FP ops -- harness-verified in R2/R3),
//   (b) EXPLICIT depth-4 register pipeline in both scan passes (named regs,
//       static indices) so 4 loads/wave stay in flight regardless of compiler
//       scheduling -> 16 outstanding per SIMD at 4 waves/SIMD.
// Selection logic = R1's verified two-pass wave-global threshold:
//   pass 1: per-lane fminf running min of exact d2 (point->lane map p=t*64+l).
//   cutoff: 16th smallest distinct lane-min (valid top-16 upper bound).
//   pass 2: recompute d2 (bit-identical), ballot-compact d2<=cutoff into LDS.
//   merge:  16-round wave-min mark-and-rescan -> exact top-16 ascending.
// d2 matches numpy's einsum C kernel bit-for-bit (verified R8):
//   dot: DESCENDING no-FMA; qq/kk: plain squares, ASCENDING add;
//   d2 = (qq - 2*dot) + kk.
__global__ __launch_bounds__(256) void k_knn(const float* __restrict__ qpos,
                                             const float* __restrict__ kpos,
                                             const float* __restrict__ W1,
                                             const float* __restrict__ b1,
                                             float* __restrict__ ws) {
  __shared__ unsigned long long cbuf[4][256];
  const int tid = threadIdx.x;
  const int w = tid >> 6, l = tid & 63;
  const int q = (int)blockIdx.x * 4 + w;
  const int b = q >> 10;

  const float4* kp4 = (const float4*)(ws + OFF_G) + (size_t)b * NPTS;
  const float* kp = kpos + (size_t)b * NPTS * 3;

  const float* qp = qpos + (size_t)q * 3;
  const float qx = qp[0], qy = qp[1], qz = qp[2];
  const float qq = __fadd_rn(__fadd_rn(__fmul_rn(qx, qx), __fmul_rn(qy, qy)), __fmul_rn(qz, qz));

#define D2_OF(cc) \
  __fadd_rn(__fsub_rn(qq, __fmul_rn(2.0f, \
    __fadd_rn(__fadd_rn(__fmul_rn(qz, (cc).z), __fmul_rn(qy, (cc).y)), __fmul_rn(qx, (cc).x)))), (cc).w)

  // ---- pass 1: per-lane min of exact d2, depth-4 register pipeline ----
  // Note: final-iteration prefetch reads 256 float4 past this batch's kp4;
  // for b=3 that is still inside ws (OFF_G region + slack < OFF_WVT). Values
  // are discarded.
  float mn = 3.4e38f;
  {
    const float4* p0 = kp4 + l;
    float4 c0 = p0[0], c1 = p0[64], c2 = p0[128], c3 = p0[192];
    const float4* nx = p0 + 256;
    for (int t = 0; t < 64; ++t) {
      float d2;
      d2 = D2_OF(c0); c0 = nx[0];   mn = fminf(mn, d2);
      d2 = D2_OF(c1); c1 = nx[64];  mn = fminf(mn, d2);
      d2 = D2_OF(c2); c2 = nx[128]; mn = fminf(mn, d2);
      d2 = D2_OF(c3); c3 = nx[192]; mn = fminf(mn, d2);
      nx += 256;
    }
  }

  // ---- cutoff = 16th smallest distinct lane-min (wave-min + knockout) ----
  float v = mn, cutoff = 0.f;
  for (int r = 0; r < 16; ++r) {
    float m = v;
#pragma unroll
    for (int s = 1; s <= 32; s <<= 1) m = fminf(m, __shfl_xor(m, s, 64));
    cutoff = m;
    if (v == m) v = 3.4e38f;
  }

  // ---- pass 2: ballot-compact candidates with d2 <= cutoff into LDS ----
  int cnt = 0;
#define COMPACT_PT(d2v, pp)                                                    \
  {                                                                            \
    const bool pred = (d2v <= cutoff);                                         \
    const unsigned long long mask = __ballot(pred);                            \
    if (pred) {                                                                \
      const int off = __builtin_amdgcn_mbcnt_hi((unsigned int)(mask >> 32),    \
                      __builtin_amdgcn_mbcnt_lo((unsigned int)mask, 0));       \
      unsigned int u = __float_as_uint(d2v);                                   \
      u ^= (unsigned int)((int)u >> 31) | 0x80000000u;                         \
      const int pos = cnt + off;                                               \
      if (pos < 256) cbuf[w][pos] = ((unsigned long long)u << 32) | (unsigned int)(pp); \
    }                                                                          \
    cnt += (int)__popcll(mask);                                                \
  }
  {
    const float4* p0 = kp4 + l;
    float4 c0 = p0[0], c1 = p0[64], c2 = p0[128], c3 = p0[192];
    const float4* nx = p0 + 256;
    int p = l;
    for (int t = 0; t < 64; ++t) {
      float d2;
      d2 = D2_OF(c0); c0 = nx[0];   COMPACT_PT(d2, p);       
      d2 = D2_OF(c1); c1 = nx[64];  COMPACT_PT(d2, p + 64);
      d2 = D2_OF(c2); c2 = nx[128]; COMPACT_PT(d2, p + 128);
      d2 = D2_OF(c3); c3 = nx[192]; COMPACT_PT(d2, p + 192);
      nx += 256;
      p += 256;
    }
  }
#undef COMPACT_PT
#undef D2_OF
  if (cnt > 256) cnt = 256;

  // ---- merge: 16 rounds of wave-min over candidates, mark-and-rescan ----
  unsigned long long cand[4];
#pragma unroll
  for (int i = 0; i < 4; ++i) {
    const int pos = l + i * 64;
    cand[i] = (pos < cnt) ? cbuf[w][pos] : ~0ull;
  }
  unsigned long long lmin = cand[0]; int lpos = 0;
#pragma unroll
  for (int i = 1; i < 4; ++i) { if (cand[i] < lmin) { lmin = cand[i]; lpos = i; } }
  unsigned long long sel64 = 0;
  for (int r = 0; r < 16; ++r) {
    const unsigned long long m = wavemin_u64(lmin);
    if (l == r) sel64 = m;
    if (lmin == m) {
#pragma unroll
      for (int i = 0; i < 4; ++i) cand[i] = (lpos == i) ? ~0ull : cand[i];
      lmin = cand[0]; lpos = 0;
#pragma unroll
      for (int i = 1; i < 4; ++i) { if (cand[i] < lmin) { lmin = cand[i]; lpos = i; } }
    }
  }
  const int myidx = (int)(sel64 & 0xffffffffull);
  if (l < 16) ((int*)(ws + OFF_IDX))[q * 16 + l] = myidx;

  // scores: j = l&15, 4 replicas each cover 32 of the 128 pe terms
  const int j = l & 15;
  const int pj = __shfl(myidx, j, 64);
  const float* kpj = kp + (size_t)pj * 3;
  const float rx = qx - kpj[0];
  const float ry = qy - kpj[1];
  const float rz = qz - kpj[2];
  float pe = 0.f;
  const int i0 = (l >> 4) * 32;
  for (int i = i0; i < i0 + 32; ++i) {
    float hh = fmaf(rx, W1[i * 3 + 0], fmaf(ry, W1[i * 3 + 1], fmaf(rz, W1[i * 3 + 2], b1[i])));
    hh = fmaxf(hh, 0.f);
    pe = fmaf(hh, ws[OFF_W2S + i], pe);
  }
  pe += __shfl_xor(pe, 16, 64);
  pe += __shfl_xor(pe, 32, 64);
  float score = ws[OFF_QSUM + q] - ws[OFF_KSUM + b * NPTS + pj] + pe + ws[OFF_SCL + 2];
  float mx = score;
  mx = fmaxf(mx, __shfl_xor(mx, 1, 64));
  mx = fmaxf(mx, __shfl_xor(mx, 2, 64));
  mx = fmaxf(mx, __shfl_xor(mx, 4, 64));
  mx = fmaxf(mx, __shfl_xor(mx, 8, 64));
  const float e = expf(score - mx);
  float se = e;
  se += __shfl_xor(se, 1, 64);
  se += __shfl_xor(se, 2, 64);
  se += __shfl_xor(se, 4, 64);
  se += __shfl_xor(se, 8, 64);
  const float attn = e / se;
  if (l < 16) {
    ws[OFF_ATTN + q * 16 + l] = attn;
    atomicAdd(&ws[OFF_COL + b * 16 + l], attn);
  }
}

// ---------- K4: normalize attn, gather-weight k_feat rows -> g, asum ----------
__global__ __launch_bounds__(256) void k_gather(const float* __restrict__ kf,
                                                float* __restrict__ ws) {
  const int tid = threadIdx.x;
  const int w = tid >> 6, l = tid & 63;
  const int q = (int)blockIdx.x * 4 + w;
  const int b = q >> 10;
  float a = 0.f;
  int pidx = 0;
  if (l < 16) {
    a = ws[OFF_ATTN + q * 16 + l] / (ws[OFF_COL + b * 16 + l] + EPSF);
    pidx = ((const int*)(ws + OFF_IDX))[q * 16 + l];
  }
  float asum = a;
  asum += __shfl_xor(asum, 1, 64);
  asum += __shfl_xor(asum, 2, 64);
  asum += __shfl_xor(asum, 4, 64);
  asum += __shfl_xor(asum, 8, 64);
  if (l == 0) ws[OFF_ASUM + q] = asum;
  const float* kb = kf + (size_t)b * NPTS * DD;
  float acc0 = 0.f, acc1 = 0.f;
#pragma unroll
  for (int jj = 0; jj < 16; ++jj) {
    const float aj = __shfl(a, jj, 64);
    const int pj = __shfl(pidx, jj, 64);
    const float* row = kb + (size_t)pj * DD;
    acc0 = fmaf(aj, row[l], acc0);
    acc1 = fmaf(aj, row[64 + l], acc1);
  }
  ws[OFF_G + (size_t)q * DD + l] = acc0;
  ws[OFF_G + (size_t)q * DD + 64 + l] = acc1;
}

// ---------- K5: out = g @ Wv^T + asum * bv ----------
__global__ __launch_bounds__(256) void k_out(const float* __restrict__ bv,
                                             const float* __restrict__ ws,
                                             float* __restrict__ out) {
  __shared__ float xg[16 * 128];
  __shared__ float as_s[16];
  const int tid = threadIdx.x;
  const int rbase = (int)blockIdx.x * 16;
  for (int e = tid; e < 16 * 128; e += 256) xg[e] = ws[OFF_G + (size_t)rbase * DD + e];
  if (tid < 16) as_s[tid] = ws[OFF_ASUM + rbase + tid];
  __syncthreads();
  const int o = tid & 127, rg = tid >> 7;
  const float bvo = bv[o];
  float acc[8];
#pragma unroll
  for (int r = 0; r < 8; ++r) acc[r] = as_s[rg * 8 + r] * bvo;
  for (int i = 0; i < DD; ++i) {
    const float wv = ws[OFF_WVT + i * DD + o];
#pragma unroll
    for (int r = 0; r < 8; ++r) acc[r] = fmaf(wv, xg[(rg * 8 + r) * 128 + i], acc[r]);
  }
#pragma unroll
  for (int r = 0; r < 8; ++r) out[(size_t)(rbase + rg * 8 + r) * DD + o] = acc[r];
}

extern "C" void kernel_launch(void* const* d_in, const int* in_sizes, int n_in,
                              void* d_out, int out_size, void* d_ws, size_t ws_size,
                              hipStream_t stream) {
  const float* qf   = (const float*)d_in[0];
  const float* kf   = (const float*)d_in[1];
  const float* qpos = (const float*)d_in[2];
  const float* kpos = (const float*)d_in[3];
  const float* Wq   = (const float*)d_in[4];
  const float* bq   = (const float*)d_in[5];
  const float* Wk   = (const float*)d_in[6];
  const float* bk   = (const float*)d_in[7];
  const float* Wv   = (const float*)d_in[8];
  const float* bv   = (const float*)d_in[9];
  const float* W1   = (const float*)d_in[10];
  const float* b1   = (const float*)d_in[11];
  const float* W2   = (const float*)d_in[12];
  const float* b2   = (const float*)d_in[13];
  float* ws  = (float*)d_ws;
  float* out = (float*)d_out;

  k_prep<<<128, 128, 0, stream>>>(Wq, bq, Wk, bk, Wv, W2, b2, ws);
  k_rowsums<<<1024, 256, 0, stream>>>(kf, qf, kpos, ws);
  k_knn<<<1024, 256, 0, stream>>>(qpos, kpos, W1, b1, ws);
  k_gather<<<1024, 256, 0, stream>>>(kf, ws);
  k_out<<<256, 256, 0, stream>>>(bv, ws, out);
}

// Round 5
// 216.139 us; speedup vs baseline: 1.5676x; 1.0142x over previous
//
#include <hip/hip_runtime.h>
#include <hip/hip_bf16.h>

#define BB 4
#define SS 1024
#define NPTS 16384
#define DD 128
#define EPSF 1e-6f

// ws layout (float element offsets), total ~2.99 MB
#define OFF_CQ     0        // 128  colsum(Wq)
#define OFF_CK     128      // 128  colsum(Wk)
#define OFF_W2S    256      // 128  colsum(W2)
#define OFF_SCL    384      // 8    [0]=sum(bq) [1]=sum(bk) [2]=sum(b2)
#define OFF_COL    448      // 64   colsum of attn over S, per (b,j)
#define OFF_QSUM   512      // 4096
#define OFF_KSUM   4608     // 65536
#define OFF_IDX    70144    // 65536 (int)
#define OFF_ATTN   135680   // 65536
#define OFF_ASUM   201216   // 4096
#define OFF_G      205312   // 524288 (k_gather output; during k_knn reused as kp4: (x,y,z,kk) per point, 262144 floats)
#define OFF_WVT    729600   // 16384 (Wv transposed)

__device__ __forceinline__ unsigned long long shflxor_u64(unsigned long long v, int m) {
  unsigned int lo = (unsigned int)(v & 0xffffffffull);
  unsigned int hi = (unsigned int)(v >> 32);
  lo = (unsigned int)__shfl_xor((int)lo, m, 64);
  hi = (unsigned int)__shfl_xor((int)hi, m, 64);
  return ((unsigned long long)hi << 32) | (unsigned long long)lo;
}

__device__ __forceinline__ unsigned long long u64min(unsigned long long a, unsigned long long b) {
  return a < b ? a : b;
}

__device__ __forceinline__ unsigned long long wavemin_u64(unsigned long long v) {
#pragma unroll
  for (int m = 1; m <= 32; m <<= 1) v = u64min(v, shflxor_u64(v, m));
  return v;
}

// ---------- K1: column sums, bias sums, Wv transpose, zero colsum ----------
// 128 blocks x 128 threads: block j = output column j
__global__ __launch_bounds__(128) void k_prep(const float* __restrict__ Wq, const float* __restrict__ bq,
                       const float* __restrict__ Wk, const float* __restrict__ bk,
                       const float* __restrict__ Wv, const float* __restrict__ W2,
                       const float* __restrict__ b2, float* __restrict__ ws) {
  const int j = (int)blockIdx.x;
  const int t = threadIdx.x;
  __shared__ float pr[6];
  __shared__ float pb[6];
  float s0 = Wq[t * DD + j], s1 = Wk[t * DD + j], s2 = W2[t * DD + j];
#pragma unroll
  for (int m = 1; m <= 32; m <<= 1) {
    s0 += __shfl_xor(s0, m, 64);
    s1 += __shfl_xor(s1, m, 64);
    s2 += __shfl_xor(s2, m, 64);
  }
  if ((t & 63) == 0) { const int wv = t >> 6; pr[wv*3+0]=s0; pr[wv*3+1]=s1; pr[wv*3+2]=s2; }
  __syncthreads();
  if (t == 0) {
    ws[OFF_CQ + j]  = pr[0] + pr[3];
    ws[OFF_CK + j]  = pr[1] + pr[4];
    ws[OFF_W2S + j] = pr[2] + pr[5];
  }
  ws[OFF_WVT + j * DD + t] = Wv[t * DD + j];
  if (j == 1 && t < 64) ws[OFF_COL + t] = 0.f;
  if (j == 0) {
    float a0 = bq[t], a1 = bk[t], a2 = b2[t];
#pragma unroll
    for (int m = 1; m <= 32; m <<= 1) {
      a0 += __shfl_xor(a0, m, 64);
      a1 += __shfl_xor(a1, m, 64);
      a2 += __shfl_xor(a2, m, 64);
    }
    if ((t & 63) == 0) { const int wv = t >> 6; pb[wv*3+0]=a0; pb[wv*3+1]=a1; pb[wv*3+2]=a2; }
    __syncthreads();
    if (t == 0) {
      ws[OFF_SCL + 0] = pb[0] + pb[3];
      ws[OFF_SCL + 1] = pb[1] + pb[4];
      ws[OFF_SCL + 2] = pb[2] + pb[5];
    }
  }
}

// ---------- K2: ksum/qsum row sums + pack kp4 = (x,y,z,kk) ----------
__global__ __launch_bounds__(256) void k_rowsums(const float* __restrict__ kf,
                                                 const float* __restrict__ qf,
                                                 const float* __restrict__ kpos,
                                                 float* __restrict__ ws) {
  const int tid = threadIdx.x;
  // pack kp4: first 65536 global threads each pack one point.
  // kk arithmetic identical to the original inline version: ((x*x + y*y) + z*z)
  const int pid = (int)blockIdx.x * 256 + tid;
  if (pid < BB * NPTS) {
    const float x = kpos[pid * 3 + 0], y = kpos[pid * 3 + 1], z = kpos[pid * 3 + 2];
    const float kk = __fadd_rn(__fadd_rn(__fmul_rn(x, x), __fmul_rn(y, y)), __fmul_rn(z, z));
    ((float4*)(ws + OFF_G))[pid] = make_float4(x, y, z, kk);
  }
  const int g = ((int)blockIdx.x * 256 + tid) >> 4;
  const int gl = tid & 15;
  const int ngroups = (int)gridDim.x * 16;
  const float bqs = ws[OFF_SCL + 0], bks = ws[OFF_SCL + 1];
  const int total = BB * NPTS + BB * SS;
  for (int row = g; row < total; row += ngroups) {
    const float* x;
    const float* c;
    if (row < BB * NPTS) { x = kf + (size_t)row * DD; c = ws + OFF_CK; }
    else                 { x = qf + (size_t)(row - BB * NPTS) * DD; c = ws + OFF_CQ; }
    float4 a  = *(const float4*)(x + gl * 4);
    float4 b  = *(const float4*)(x + 64 + gl * 4);
    float4 ca = *(const float4*)(c + gl * 4);
    float4 cb = *(const float4*)(c + 64 + gl * 4);
    float s = a.x * ca.x + a.y * ca.y + a.z * ca.z + a.w * ca.w
            + b.x * cb.x + b.y * cb.y + b.z * cb.z + b.w * cb.w;
    s += __shfl_xor(s, 1, 64);
    s += __shfl_xor(s, 2, 64);
    s += __shfl_xor(s, 4, 64);
    s += __shfl_xor(s, 8, 64);
    if (gl == 0) {
      if (row < BB * NPTS) ws[OFF_KSUM + row] = s + bks;
      else                 ws[OFF_QSUM + (row - BB * NPTS)] = s + bqs;
    }
  }
}

// ---------- K3: fused KNN + pe-sum + scores + softmax + colsum atomics ----------
// R5: R4's winning structure with 2x thread-level parallelism: each query's
// 16384-point scan is SPLIT ACROSS 2 WAVES (8192 points each, depth-4 register
// pipeline per wave). Grid 2048 blocks x 4 waves = 32 waves/CU (full capacity,
// 8 waves/SIMD) so load latency is covered by TLP on top of the pipeline.
//   pass 1: per-lane fminf running min of exact d2 over the wave's half.
//   cutoff: lane-mins exchanged via LDS; 16-round distinct-knockout over the
//           128 combined lane-minima (2 regs/lane) -> 16th smallest distinct
//           lane-min = valid upper bound on the true 16th distance. Both
//           waves of a pair compute the identical cutoff.
//   pass 2: recompute d2 (bit-identical), ballot-compact d2<=cutoff into the
//           wave's own cbuf (exact keys, cap 256).
//   merge:  pair's even wave merges both buffers (cand[8]/lane, 16-round
//           wave-min mark-and-rescan) -> exact top-16 ascending (d2, idx),
//           then runs pe/softmax/colsum epilogue (unchanged).
// d2 matches numpy's einsum C kernel bit-for-bit (verified R8):
//   dot: DESCENDING no-FMA; qq/kk: plain squares, ASCENDING add;
//   d2 = (qq - 2*dot) + kk. kk precomputed in k_rowsums with same ops.
__global__ __launch_bounds__(256, 8) void k_knn(const float* __restrict__ qpos,
                                                const float* __restrict__ kpos,
                                                const float* __restrict__ W1,
                                                const float* __restrict__ b1,
                                                float* __restrict__ ws) {
  __shared__ unsigned long long cbuf[4][256];  // per-wave candidate buffer
  __shared__ float pmins[4][64];               // per-wave lane-mins
  __shared__ int cnts[4];
  const int tid = threadIdx.x;
  const int w = tid >> 6, l = tid & 63;
  const int k = w >> 1;          // query slot within block (0,1)
  const int half = w & 1;        // which 8192-point half this wave scans
  const int q = (int)blockIdx.x * 2 + k;
  const int b = q >> 10;

  const float4* kp4 = (const float4*)(ws + OFF_G) + (size_t)b * NPTS;
  const float* kp = kpos + (size_t)b * NPTS * 3;

  const float* qp = qpos + (size_t)q * 3;
  const float qx = qp[0], qy = qp[1], qz = qp[2];
  const float qq = __fadd_rn(__fadd_rn(__fmul_rn(qx, qx), __fmul_rn(qy, qy)), __fmul_rn(qz, qz));

#define D2_OF(cc) \
  __fadd_rn(__fsub_rn(qq, __fmul_rn(2.0f, \
    __fadd_rn(__fadd_rn(__fmul_rn(qz, (cc).z), __fmul_rn(qy, (cc).y)), __fmul_rn(qx, (cc).x)))), (cc).w)

  // ---- pass 1: per-lane min of exact d2 over this wave's half ----
  // Final-iteration prefetch reads up to 256 float4 past the half: for half 0
  // that's the start of half 1; for half 1 of batch 3 it lands in ws slack
  // below OFF_WVT. Values are discarded.
  float mn = 3.4e38f;
  {
    const float4* p0 = kp4 + half * 8192 + l;
    float4 c0 = p0[0], c1 = p0[64], c2 = p0[128], c3 = p0[192];
    const float4* nx = p0 + 256;
    for (int t = 0; t < 32; ++t) {
      float d2;
      d2 = D2_OF(c0); c0 = nx[0];   mn = fminf(mn, d2);
      d2 = D2_OF(c1); c1 = nx[64];  mn = fminf(mn, d2);
      d2 = D2_OF(c2); c2 = nx[128]; mn = fminf(mn, d2);
      d2 = D2_OF(c3); c3 = nx[192]; mn = fminf(mn, d2);
      nx += 256;
    }
  }
  pmins[w][l] = mn;
  __syncthreads();

  // ---- cutoff: 16th smallest distinct over the pair's 128 lane-mins ----
  float v1 = mn, v2 = pmins[w ^ 1][l], cutoff = 0.f;
  for (int r = 0; r < 16; ++r) {
    float m = fminf(v1, v2);
#pragma unroll
    for (int s = 1; s <= 32; s <<= 1) m = fminf(m, __shfl_xor(m, s, 64));
    cutoff = m;
    if (v1 == m) v1 = 3.4e38f;
    if (v2 == m) v2 = 3.4e38f;
  }

  // ---- pass 2: ballot-compact candidates with d2 <= cutoff into own cbuf ----
  int cnt = 0;
#define COMPACT_PT(d2v, pp)                                                    \
  {                                                                            \
    const bool pred = (d2v <= cutoff);                                         \
    const unsigned long long mask = __ballot(pred);                            \
    if (pred) {                                                                \
      const int off = __builtin_amdgcn_mbcnt_hi((unsigned int)(mask >> 32),    \
                      __builtin_amdgcn_mbcnt_lo((unsigned int)mask, 0));       \
      unsigned int u = __float_as_uint(d2v);                                   \
      u ^= (unsigned int)((int)u >> 31) | 0x80000000u;                         \
      const int pos = cnt + off;                                               \
      if (pos < 256) cbuf[w][pos] = ((unsigned long long)u << 32) | (unsigned int)(pp); \
    }                                                                          \
    cnt += (int)__popcll(mask);                                                \
  }
  {
    const float4* p0 = kp4 + half * 8192 + l;
    float4 c0 = p0[0], c1 = p0[64], c2 = p0[128], c3 = p0[192];
    const float4* nx = p0 + 256;
    int p = half * 8192 + l;
    for (int t = 0; t < 32; ++t) {
      float d2;
      d2 = D2_OF(c0); c0 = nx[0];   COMPACT_PT(d2, p);
      d2 = D2_OF(c1); c1 = nx[64];  COMPACT_PT(d2, p + 64);
      d2 = D2_OF(c2); c2 = nx[128]; COMPACT_PT(d2, p + 128);
      d2 = D2_OF(c3); c3 = nx[192]; COMPACT_PT(d2, p + 192);
      nx += 256;
      p += 256;
    }
  }
#undef COMPACT_PT
#undef D2_OF
  if (cnt > 256) cnt = 256;
  if (l == 0) cnts[w] = cnt;
  __syncthreads();

  // ---- merge + epilogue: pair's even wave only ----
  if ((w & 1) == 0) {
    const int cA = cnts[w], cB = cnts[w + 1];
    unsigned long long cand[8];
#pragma unroll
    for (int i = 0; i < 4; ++i) {
      const int pos = l + i * 64;
      cand[i] = (pos < cA) ? cbuf[w][pos] : ~0ull;
    }
#pragma unroll
    for (int i = 0; i < 4; ++i) {
      const int pos = l + i * 64;
      cand[4 + i] = (pos < cB) ? cbuf[w + 1][pos] : ~0ull;
    }
    unsigned long long lmin = cand[0]; int lpos = 0;
#pragma unroll
    for (int i = 1; i < 8; ++i) { if (cand[i] < lmin) { lmin = cand[i]; lpos = i; } }
    unsigned long long sel64 = 0;
    for (int r = 0; r < 16; ++r) {
      const unsigned long long m = wavemin_u64(lmin);
      if (l == r) sel64 = m;
      if (lmin == m) {
#pragma unroll
        for (int i = 0; i < 8; ++i) cand[i] = (lpos == i) ? ~0ull : cand[i];
        lmin = cand[0]; lpos = 0;
#pragma unroll
        for (int i = 1; i < 8; ++i) { if (cand[i] < lmin) { lmin = cand[i]; lpos = i; } }
      }
    }
    const int myidx = (int)(sel64 & 0xffffffffull);
    if (l < 16) ((int*)(ws + OFF_IDX))[q * 16 + l] = myidx;

    // scores: j = l&15, 4 replicas each cover 32 of the 128 pe terms
    const int j = l & 15;
    const int pj = __shfl(myidx, j, 64);
    const float* kpj = kp + (size_t)pj * 3;
    const float rx = qx - kpj[0];
    const float ry = qy - kpj[1];
    const float rz = qz - kpj[2];
    float pe = 0.f;
    const int i0 = (l >> 4) * 32;
    for (int i = i0; i < i0 + 32; ++i) {
      float hh = fmaf(rx, W1[i * 3 + 0], fmaf(ry, W1[i * 3 + 1], fmaf(rz, W1[i * 3 + 2], b1[i])));
      hh = fmaxf(hh, 0.f);
      pe = fmaf(hh, ws[OFF_W2S + i], pe);
    }
    pe += __shfl_xor(pe, 16, 64);
    pe += __shfl_xor(pe, 32, 64);
    float score = ws[OFF_QSUM + q] - ws[OFF_KSUM + b * NPTS + pj] + pe + ws[OFF_SCL + 2];
    float mx = score;
    mx = fmaxf(mx, __shfl_xor(mx, 1, 64));
    mx = fmaxf(mx, __shfl_xor(mx, 2, 64));
    mx = fmaxf(mx, __shfl_xor(mx, 4, 64));
    mx = fmaxf(mx, __shfl_xor(mx, 8, 64));
    const float e = expf(score - mx);
    float se = e;
    se += __shfl_xor(se, 1, 64);
    se += __shfl_xor(se, 2, 64);
    se += __shfl_xor(se, 4, 64);
    se += __shfl_xor(se, 8, 64);
    const float attn = e / se;
    if (l < 16) {
      ws[OFF_ATTN + q * 16 + l] = attn;
      atomicAdd(&ws[OFF_COL + b * 16 + l], attn);
    }
  }
}

// ---------- K4: normalize attn, gather-weight k_feat rows -> g, asum ----------
__global__ __launch_bounds__(256) void k_gather(const float* __restrict__ kf,
                                                float* __restrict__ ws) {
  const int tid = threadIdx.x;
  const int w = tid >> 6, l = tid & 63;
  const int q = (int)blockIdx.x * 4 + w;
  const int b = q >> 10;
  float a = 0.f;
  int pidx = 0;
  if (l < 16) {
    a = ws[OFF_ATTN + q * 16 + l] / (ws[OFF_COL + b * 16 + l] + EPSF);
    pidx = ((const int*)(ws + OFF_IDX))[q * 16 + l];
  }
  float asum = a;
  asum += __shfl_xor(asum, 1, 64);
  asum += __shfl_xor(asum, 2, 64);
  asum += __shfl_xor(asum, 4, 64);
  asum += __shfl_xor(asum, 8, 64);
  if (l == 0) ws[OFF_ASUM + q] = asum;
  const float* kb = kf + (size_t)b * NPTS * DD;
  float acc0 = 0.f, acc1 = 0.f;
#pragma unroll
  for (int jj = 0; jj < 16; ++jj) {
    const float aj = __shfl(a, jj, 64);
    const int pj = __shfl(pidx, jj, 64);
    const float* row = kb + (size_t)pj * DD;
    acc0 = fmaf(aj, row[l], acc0);
    acc1 = fmaf(aj, row[64 + l], acc1);
  }
  ws[OFF_G + (size_t)q * DD + l] = acc0;
  ws[OFF_G + (size_t)q * DD + 64 + l] = acc1;
}

// ---------- K5: out = g @ Wv^T + asum * bv ----------
__global__ __launch_bounds__(256) void k_out(const float* __restrict__ bv,
                                             const float* __restrict__ ws,
                                             float* __restrict__ out) {
  __shared__ float xg[16 * 128];
  __shared__ float as_s[16];
  const int tid = threadIdx.x;
  const int rbase = (int)blockIdx.x * 16;
  for (int e = tid; e < 16 * 128; e += 256) xg[e] = ws[OFF_G + (size_t)rbase * DD + e];
  if (tid < 16) as_s[tid] = ws[OFF_ASUM + rbase + tid];
  __syncthreads();
  const int o = tid & 127, rg = tid >> 7;
  const float bvo = bv[o];
  float acc[8];
#pragma unroll
  for (int r = 0; r < 8; ++r) acc[r] = as_s[rg * 8 + r] * bvo;
  for (int i = 0; i < DD; ++i) {
    const float wv = ws[OFF_WVT + i * DD + o];
#pragma unroll
    for (int r = 0; r < 8; ++r) acc[r] = fmaf(wv, xg[(rg * 8 + r) * 128 + i], acc[r]);
  }
#pragma unroll
  for (int r = 0; r < 8; ++r) out[(size_t)(rbase + rg * 8 + r) * DD + o] = acc[r];
}

extern "C" void kernel_launch(void* const* d_in, const int* in_sizes, int n_in,
                              void* d_out, int out_size, void* d_ws, size_t ws_size,
                              hipStream_t stream) {
  const float* qf   = (const float*)d_in[0];
  const float* kf   = (const float*)d_in[1];
  const float* qpos = (const float*)d_in[2];
  const float* kpos = (const float*)d_in[3];
  const float* Wq   = (const float*)d_in[4];
  const float* bq   = (const float*)d_in[5];
  const float* Wk   = (const float*)d_in[6];
  const float* bk   = (const float*)d_in[7];
  const float* Wv   = (const float*)d_in[8];
  const float* bv   = (const float*)d_in[9];
  const float* W1   = (const float*)d_in[10];
  const float* b1   = (const float*)d_in[11];
  const float* W2   = (const float*)d_in[12];
  const float* b2   = (const float*)d_in[13];
  float* ws  = (float*)d_ws;
  float* out = (float*)d_out;

  k_prep<<<128, 128, 0, stream>>>(Wq, bq, Wk, bk, Wv, W2, b2, ws);
  k_rowsums<<<1024, 256, 0, stream>>>(kf, qf, kpos, ws);
  k_knn<<<2048, 256, 0, stream>>>(qpos, kpos, W1, b1, ws);
  k_gather<<<1024, 256, 0, stream>>>(kf, ws);
  k_out<<<256, 256, 0, stream>>>(bv, ws, out);
}

// Round 6
// 204.628 us; speedup vs baseline: 1.6557x; 1.0563x over previous
//
#include <hip/hip_runtime.h>
#include <hip/hip_bf16.h>

#define BB 4
#define SS 1024
#define NPTS 16384
#define DD 128
#define EPSF 1e-6f

// ws layout (float element offsets), total ~2.99 MB
#define OFF_CQ     0        // 128  colsum(Wq)
#define OFF_CK     128      // 128  colsum(Wk)
#define OFF_W2S    256      // 128  colsum(W2)
#define OFF_SCL    384      // 8    [0]=sum(bq) [1]=sum(bk) [2]=sum(b2)
#define OFF_COL    448      // 64   colsum of attn over S, per (b,j)
#define OFF_QSUM   512      // 4096
#define OFF_KSUM   4608     // 65536
#define OFF_IDX    70144    // 65536 (int)
#define OFF_ATTN   135680   // 65536
#define OFF_ASUM   201216   // 4096
#define OFF_G      205312   // 524288 (k_gather output; during k_knn reused as kp4: (x,y,z,kk) per point, 262144 floats)
#define OFF_WVT    729600   // 16384 (Wv transposed)

__device__ __forceinline__ unsigned long long shflxor_u64(unsigned long long v, int m) {
  unsigned int lo = (unsigned int)(v & 0xffffffffull);
  unsigned int hi = (unsigned int)(v >> 32);
  lo = (unsigned int)__shfl_xor((int)lo, m, 64);
  hi = (unsigned int)__shfl_xor((int)hi, m, 64);
  return ((unsigned long long)hi << 32) | (unsigned long long)lo;
}

__device__ __forceinline__ unsigned long long u64min(unsigned long long a, unsigned long long b) {
  return a < b ? a : b;
}

__device__ __forceinline__ unsigned long long wavemin_u64(unsigned long long v) {
#pragma unroll
  for (int m = 1; m <= 32; m <<= 1) v = u64min(v, shflxor_u64(v, m));
  return v;
}

// ---------- K1: column sums, bias sums, Wv transpose, zero colsum ----------
// 128 blocks x 128 threads: block j = output column j
__global__ __launch_bounds__(128) void k_prep(const float* __restrict__ Wq, const float* __restrict__ bq,
                       const float* __restrict__ Wk, const float* __restrict__ bk,
                       const float* __restrict__ Wv, const float* __restrict__ W2,
                       const float* __restrict__ b2, float* __restrict__ ws) {
  const int j = (int)blockIdx.x;
  const int t = threadIdx.x;
  __shared__ float pr[6];
  __shared__ float pb[6];
  float s0 = Wq[t * DD + j], s1 = Wk[t * DD + j], s2 = W2[t * DD + j];
#pragma unroll
  for (int m = 1; m <= 32; m <<= 1) {
    s0 += __shfl_xor(s0, m, 64);
    s1 += __shfl_xor(s1, m, 64);
    s2 += __shfl_xor(s2, m, 64);
  }
  if ((t & 63) == 0) { const int wv = t >> 6; pr[wv*3+0]=s0; pr[wv*3+1]=s1; pr[wv*3+2]=s2; }
  __syncthreads();
  if (t == 0) {
    ws[OFF_CQ + j]  = pr[0] + pr[3];
    ws[OFF_CK + j]  = pr[1] + pr[4];
    ws[OFF_W2S + j] = pr[2] + pr[5];
  }
  ws[OFF_WVT + j * DD + t] = Wv[t * DD + j];
  if (j == 1 && t < 64) ws[OFF_COL + t] = 0.f;
  if (j == 0) {
    float a0 = bq[t], a1 = bk[t], a2 = b2[t];
#pragma unroll
    for (int m = 1; m <= 32; m <<= 1) {
      a0 += __shfl_xor(a0, m, 64);
      a1 += __shfl_xor(a1, m, 64);
      a2 += __shfl_xor(a2, m, 64);
    }
    if ((t & 63) == 0) { const int wv = t >> 6; pb[wv*3+0]=a0; pb[wv*3+1]=a1; pb[wv*3+2]=a2; }
    __syncthreads();
    if (t == 0) {
      ws[OFF_SCL + 0] = pb[0] + pb[3];
      ws[OFF_SCL + 1] = pb[1] + pb[4];
      ws[OFF_SCL + 2] = pb[2] + pb[5];
    }
  }
}

// ---------- K2: ksum/qsum row sums + pack kp4 = (x,y,z,kk) ----------
__global__ __launch_bounds__(256) void k_rowsums(const float* __restrict__ kf,
                                                 const float* __restrict__ qf,
                                                 const float* __restrict__ kpos,
                                                 float* __restrict__ ws) {
  const int tid = threadIdx.x;
  // pack kp4: first 65536 global threads each pack one point.
  // kk arithmetic identical to the original inline version: ((x*x + y*y) + z*z)
  const int pid = (int)blockIdx.x * 256 + tid;
  if (pid < BB * NPTS) {
    const float x = kpos[pid * 3 + 0], y = kpos[pid * 3 + 1], z = kpos[pid * 3 + 2];
    const float kk = __fadd_rn(__fadd_rn(__fmul_rn(x, x), __fmul_rn(y, y)), __fmul_rn(z, z));
    ((float4*)(ws + OFF_G))[pid] = make_float4(x, y, z, kk);
  }
  const int g = ((int)blockIdx.x * 256 + tid) >> 4;
  const int gl = tid & 15;
  const int ngroups = (int)gridDim.x * 16;
  const float bqs = ws[OFF_SCL + 0], bks = ws[OFF_SCL + 1];
  const int total = BB * NPTS + BB * SS;
  for (int row = g; row < total; row += ngroups) {
    const float* x;
    const float* c;
    if (row < BB * NPTS) { x = kf + (size_t)row * DD; c = ws + OFF_CK; }
    else                 { x = qf + (size_t)(row - BB * NPTS) * DD; c = ws + OFF_CQ; }
    float4 a  = *(const float4*)(x + gl * 4);
    float4 b  = *(const float4*)(x + 64 + gl * 4);
    float4 ca = *(const float4*)(c + gl * 4);
    float4 cb = *(const float4*)(c + 64 + gl * 4);
    float s = a.x * ca.x + a.y * ca.y + a.z * ca.z + a.w * ca.w
            + b.x * cb.x + b.y * cb.y + b.z * cb.z + b.w * cb.w;
    s += __shfl_xor(s, 1, 64);
    s += __shfl_xor(s, 2, 64);
    s += __shfl_xor(s, 4, 64);
    s += __shfl_xor(s, 8, 64);
    if (gl == 0) {
      if (row < BB * NPTS) ws[OFF_KSUM + row] = s + bks;
      else                 ws[OFF_QSUM + (row - BB * NPTS)] = s + bqs;
    }
  }
}

// ---------- K3: fused KNN + pe-sum + scores + softmax + colsum atomics ----------
// R6: amortize point loads over 4 queries (R2's idea) at R4/R5's occupancy
// with R4's depth-4 register pipeline. L1 traffic /4 vs R5 (the measured
// bottleneck: R5 doubled occupancy, time flat, VALUBusy 37% -> L1-pipe-bound).
// Block = 4 waves = 4 queries; wave w scans slice w (4096 pts) computing d2
// for ALL 4 queries per loaded point.
//   pass 1: per-lane fminf running min of exact d2, per query, over the slice.
//   cutoff: per query, 16th smallest DISTINCT over the 256 lane-minima
//           (4 waves x 64 lanes via LDS). Lanes own disjoint point sets, so
//           16 distinct lane-min values => >=16 distinct points <= cutoff =>
//           cutoff >= true 16th distance. All waves compute identical values.
//   pass 2: recompute d2 (bit-identical), ballot-compact d2<=cutoff into
//           per-(query,wave) buffers (cap 64; expected ~5 per slice).
//   merge:  wave qi merges query qi's 4 buffers (<=256 cands, cand[4]/lane,
//           16-round wave-min mark-and-rescan). Keys are exact (d2,idx) u64s
//           so ordering is total -> identical ascending top-16 as R4/R5.
// d2 matches numpy's einsum C kernel bit-for-bit (verified R8):
//   dot: DESCENDING no-FMA; qq/kk: plain squares, ASCENDING add;
//   d2 = (qq - 2*dot) + kk. kk precomputed in k_rowsums with same ops.
__global__ __launch_bounds__(256, 4) void k_knn(const float* __restrict__ qpos,
                                                const float* __restrict__ kpos,
                                                const float* __restrict__ W1,
                                                const float* __restrict__ b1,
                                                float* __restrict__ ws) {
  __shared__ unsigned long long cbuf[4][4][64];  // [query][wave][slot]
  __shared__ float pmins[4][4][64];              // [wave][query][lane]
  __shared__ int cnts[4][4];                     // [query][wave]
  const int tid = threadIdx.x;
  const int w = tid >> 6, l = tid & 63;
  const int qbase = (int)blockIdx.x * 4;
  const int b = qbase >> 10;   // 1024 % 4 == 0: all 4 queries in same batch

  const float4* kp4 = (const float4*)(ws + OFF_G) + (size_t)b * NPTS;
  const float* kp = kpos + (size_t)b * NPTS * 3;

  const float* qp0 = qpos + (size_t)(qbase + 0) * 3;
  const float* qp1 = qpos + (size_t)(qbase + 1) * 3;
  const float* qp2 = qpos + (size_t)(qbase + 2) * 3;
  const float* qp3 = qpos + (size_t)(qbase + 3) * 3;
  const float qx0 = qp0[0], qy0 = qp0[1], qz0 = qp0[2];
  const float qx1 = qp1[0], qy1 = qp1[1], qz1 = qp1[2];
  const float qx2 = qp2[0], qy2 = qp2[1], qz2 = qp2[2];
  const float qx3 = qp3[0], qy3 = qp3[1], qz3 = qp3[2];
  const float qq0 = __fadd_rn(__fadd_rn(__fmul_rn(qx0, qx0), __fmul_rn(qy0, qy0)), __fmul_rn(qz0, qz0));
  const float qq1 = __fadd_rn(__fadd_rn(__fmul_rn(qx1, qx1), __fmul_rn(qy1, qy1)), __fmul_rn(qz1, qz1));
  const float qq2 = __fadd_rn(__fadd_rn(__fmul_rn(qx2, qx2), __fmul_rn(qy2, qy2)), __fmul_rn(qz2, qz2));
  const float qq3 = __fadd_rn(__fadd_rn(__fmul_rn(qx3, qx3), __fmul_rn(qy3, qy3)), __fmul_rn(qz3, qz3));

  const int sbase = w * 4096;

#define D2Q(cc, QX, QY, QZ, QQ) \
  __fadd_rn(__fsub_rn(QQ, __fmul_rn(2.0f, \
    __fadd_rn(__fadd_rn(__fmul_rn(QZ, (cc).z), __fmul_rn(QY, (cc).y)), __fmul_rn(QX, (cc).x)))), (cc).w)

  // ---- pass 1: per-lane min of exact d2, 4 queries per loaded point ----
  // Final-iteration prefetch reads up to ~256 float4 past the slice; for
  // wave 3 of batch 3 that lands in ws slack below OFF_WVT. Discarded.
  float mn0 = 3.4e38f, mn1 = 3.4e38f, mn2 = 3.4e38f, mn3 = 3.4e38f;
  {
    const float4* p0 = kp4 + sbase + l;
    float4 c0 = p0[0], c1 = p0[64], c2 = p0[128], c3 = p0[192];
    const float4* nx = p0 + 256;
#define P1_PT(cc, RELOAD)                                      \
    {                                                          \
      const float d20 = D2Q(cc, qx0, qy0, qz0, qq0);           \
      const float d21 = D2Q(cc, qx1, qy1, qz1, qq1);           \
      const float d22 = D2Q(cc, qx2, qy2, qz2, qq2);           \
      const float d23 = D2Q(cc, qx3, qy3, qz3, qq3);           \
      cc = RELOAD;                                             \
      mn0 = fminf(mn0, d20);                                   \
      mn1 = fminf(mn1, d21);                                   \
      mn2 = fminf(mn2, d22);                                   \
      mn3 = fminf(mn3, d23);                                   \
    }
    for (int t = 0; t < 16; ++t) {
      P1_PT(c0, nx[0])
      P1_PT(c1, nx[64])
      P1_PT(c2, nx[128])
      P1_PT(c3, nx[192])
      nx += 256;
    }
#undef P1_PT
  }
  pmins[w][0][l] = mn0;
  pmins[w][1][l] = mn1;
  pmins[w][2][l] = mn2;
  pmins[w][3][l] = mn3;
  __syncthreads();

  // ---- cutoffs: per query, 16th smallest distinct over 256 lane-mins ----
  float cut0, cut1, cut2, cut3;
#define CUTOFF16(qi, cutvar)                                                 \
  {                                                                          \
    float v0 = pmins[0][qi][l], v1 = pmins[1][qi][l];                        \
    float v2 = pmins[2][qi][l], v3 = pmins[3][qi][l];                        \
    float cu = 0.f;                                                          \
    for (int r = 0; r < 16; ++r) {                                           \
      float m = fminf(fminf(v0, v1), fminf(v2, v3));                         \
      _Pragma("unroll")                                                      \
      for (int s = 1; s <= 32; s <<= 1) m = fminf(m, __shfl_xor(m, s, 64));  \
      cu = m;                                                                \
      if (v0 == m) v0 = 3.4e38f;                                             \
      if (v1 == m) v1 = 3.4e38f;                                             \
      if (v2 == m) v2 = 3.4e38f;                                             \
      if (v3 == m) v3 = 3.4e38f;                                             \
    }                                                                        \
    cutvar = cu;                                                             \
  }
  CUTOFF16(0, cut0)
  CUTOFF16(1, cut1)
  CUTOFF16(2, cut2)
  CUTOFF16(3, cut3)
#undef CUTOFF16

  // ---- pass 2: ballot-compact candidates per query into own buffers ----
  int cnt0 = 0, cnt1 = 0, cnt2 = 0, cnt3 = 0;
#define COMPACT_PT(qi, d2v, cutv, cntv, pp)                                    \
  {                                                                            \
    const bool pred = (d2v <= cutv);                                           \
    const unsigned long long mask = __ballot(pred);                            \
    if (pred) {                                                                \
      const int off = __builtin_amdgcn_mbcnt_hi((unsigned int)(mask >> 32),    \
                      __builtin_amdgcn_mbcnt_lo((unsigned int)mask, 0));       \
      unsigned int u = __float_as_uint(d2v);                                   \
      u ^= (unsigned int)((int)u >> 31) | 0x80000000u;                         \
      const int pos = cntv + off;                                              \
      if (pos < 64) cbuf[qi][w][pos] = ((unsigned long long)u << 32) | (unsigned int)(pp); \
    }                                                                          \
    cntv += (int)__popcll(mask);                                               \
  }
  {
    const float4* p0 = kp4 + sbase + l;
    float4 c0 = p0[0], c1 = p0[64], c2 = p0[128], c3 = p0[192];
    const float4* nx = p0 + 256;
    int p = sbase + l;
#define P2_PT(cc, RELOAD, POFF)                                  \
    {                                                            \
      const float d20 = D2Q(cc, qx0, qy0, qz0, qq0);             \
      const float d21 = D2Q(cc, qx1, qy1, qz1, qq1);             \
      const float d22 = D2Q(cc, qx2, qy2, qz2, qq2);             \
      const float d23 = D2Q(cc, qx3, qy3, qz3, qq3);             \
      cc = RELOAD;                                               \
      COMPACT_PT(0, d20, cut0, cnt0, p + POFF)                   \
      COMPACT_PT(1, d21, cut1, cnt1, p + POFF)                   \
      COMPACT_PT(2, d22, cut2, cnt2, p + POFF)                   \
      COMPACT_PT(3, d23, cut3, cnt3, p + POFF)                   \
    }
    for (int t = 0; t < 16; ++t) {
      P2_PT(c0, nx[0], 0)
      P2_PT(c1, nx[64], 64)
      P2_PT(c2, nx[128], 128)
      P2_PT(c3, nx[192], 192)
      nx += 256;
      p += 256;
    }
#undef P2_PT
  }
#undef COMPACT_PT
#undef D2Q
  if (cnt0 > 64) cnt0 = 64;
  if (cnt1 > 64) cnt1 = 64;
  if (cnt2 > 64) cnt2 = 64;
  if (cnt3 > 64) cnt3 = 64;
  if (l == 0) {
    cnts[0][w] = cnt0;
    cnts[1][w] = cnt1;
    cnts[2][w] = cnt2;
    cnts[3][w] = cnt3;
  }
  __syncthreads();

  // ---- merge + epilogue: wave qi = w owns query qbase + w ----
  const int qi = w;
  const int q = qbase + qi;
  unsigned long long cand[4];
#pragma unroll
  for (int i = 0; i < 4; ++i) {
    const int cn = cnts[qi][i];
    cand[i] = (l < cn) ? cbuf[qi][i][l] : ~0ull;
  }
  unsigned long long lmin = cand[0]; int lpos = 0;
#pragma unroll
  for (int i = 1; i < 4; ++i) { if (cand[i] < lmin) { lmin = cand[i]; lpos = i; } }
  unsigned long long sel64 = 0;
  for (int r = 0; r < 16; ++r) {
    const unsigned long long m = wavemin_u64(lmin);
    if (l == r) sel64 = m;
    if (lmin == m) {
#pragma unroll
      for (int i = 0; i < 4; ++i) cand[i] = (lpos == i) ? ~0ull : cand[i];
      lmin = cand[0]; lpos = 0;
#pragma unroll
      for (int i = 1; i < 4; ++i) { if (cand[i] < lmin) { lmin = cand[i]; lpos = i; } }
    }
  }
  const int myidx = (int)(sel64 & 0xffffffffull);
  if (l < 16) ((int*)(ws + OFF_IDX))[q * 16 + l] = myidx;

  // scores: j = l&15, 4 replicas each cover 32 of the 128 pe terms
  const float gx = (qi == 0) ? qx0 : ((qi == 1) ? qx1 : ((qi == 2) ? qx2 : qx3));
  const float gy = (qi == 0) ? qy0 : ((qi == 1) ? qy1 : ((qi == 2) ? qy2 : qy3));
  const float gz = (qi == 0) ? qz0 : ((qi == 1) ? qz1 : ((qi == 2) ? qz2 : qz3));
  const int j = l & 15;
  const int pj = __shfl(myidx, j, 64);
  const float* kpj = kp + (size_t)pj * 3;
  const float rx = gx - kpj[0];
  const float ry = gy - kpj[1];
  const float rz = gz - kpj[2];
  float pe = 0.f;
  const int i0 = (l >> 4) * 32;
  for (int i = i0; i < i0 + 32; ++i) {
    float hh = fmaf(rx, W1[i * 3 + 0], fmaf(ry, W1[i * 3 + 1], fmaf(rz, W1[i * 3 + 2], b1[i])));
    hh = fmaxf(hh, 0.f);
    pe = fmaf(hh, ws[OFF_W2S + i], pe);
  }
  pe += __shfl_xor(pe, 16, 64);
  pe += __shfl_xor(pe, 32, 64);
  float score = ws[OFF_QSUM + q] - ws[OFF_KSUM + b * NPTS + pj] + pe + ws[OFF_SCL + 2];
  float mx = score;
  mx = fmaxf(mx, __shfl_xor(mx, 1, 64));
  mx = fmaxf(mx, __shfl_xor(mx, 2, 64));
  mx = fmaxf(mx, __shfl_xor(mx, 4, 64));
  mx = fmaxf(mx, __shfl_xor(mx, 8, 64));
  const float e = expf(score - mx);
  float se = e;
  se += __shfl_xor(se, 1, 64);
  se += __shfl_xor(se, 2, 64);
  se += __shfl_xor(se, 4, 64);
  se += __shfl_xor(se, 8, 64);
  const float attn = e / se;
  if (l < 16) {
    ws[OFF_ATTN + q * 16 + l] = attn;
    atomicAdd(&ws[OFF_COL + b * 16 + l], attn);
  }
}

// ---------- K4: normalize attn, gather-weight k_feat rows -> g, asum ----------
__global__ __launch_bounds__(256) void k_gather(const float* __restrict__ kf,
                                                float* __restrict__ ws) {
  const int tid = threadIdx.x;
  const int w = tid >> 6, l = tid & 63;
  const int q = (int)blockIdx.x * 4 + w;
  const int b = q >> 10;
  float a = 0.f;
  int pidx = 0;
  if (l < 16) {
    a = ws[OFF_ATTN + q * 16 + l] / (ws[OFF_COL + b * 16 + l] + EPSF);
    pidx = ((const int*)(ws + OFF_IDX))[q * 16 + l];
  }
  float asum = a;
  asum += __shfl_xor(asum, 1, 64);
  asum += __shfl_xor(asum, 2, 64);
  asum += __shfl_xor(asum, 4, 64);
  asum += __shfl_xor(asum, 8, 64);
  if (l == 0) ws[OFF_ASUM + q] = asum;
  const float* kb = kf + (size_t)b * NPTS * DD;
  float acc0 = 0.f, acc1 = 0.f;
#pragma unroll
  for (int jj = 0; jj < 16; ++jj) {
    const float aj = __shfl(a, jj, 64);
    const int pj = __shfl(pidx, jj, 64);
    const float* row = kb + (size_t)pj * DD;
    acc0 = fmaf(aj, row[l], acc0);
    acc1 = fmaf(aj, row[64 + l], acc1);
  }
  ws[OFF_G + (size_t)q * DD + l] = acc0;
  ws[OFF_G + (size_t)q * DD + 64 + l] = acc1;
}

// ---------- K5: out = g @ Wv^T + asum * bv ----------
__global__ __launch_bounds__(256) void k_out(const float* __restrict__ bv,
                                             const float* __restrict__ ws,
                                             float* __restrict__ out) {
  __shared__ float xg[16 * 128];
  __shared__ float as_s[16];
  const int tid = threadIdx.x;
  const int rbase = (int)blockIdx.x * 16;
  for (int e = tid; e < 16 * 128; e += 256) xg[e] = ws[OFF_G + (size_t)rbase * DD + e];
  if (tid < 16) as_s[tid] = ws[OFF_ASUM + rbase + tid];
  __syncthreads();
  const int o = tid & 127, rg = tid >> 7;
  const float bvo = bv[o];
  float acc[8];
#pragma unroll
  for (int r = 0; r < 8; ++r) acc[r] = as_s[rg * 8 + r] * bvo;
  for (int i = 0; i < DD; ++i) {
    const float wv = ws[OFF_WVT + i * DD + o];
#pragma unroll
    for (int r = 0; r < 8; ++r) acc[r] = fmaf(wv, xg[(rg * 8 + r) * 128 + i], acc[r]);
  }
#pragma unroll
  for (int r = 0; r < 8; ++r) out[(size_t)(rbase + rg * 8 + r) * DD + o] = acc[r];
}

extern "C" void kernel_launch(void* const* d_in, const int* in_sizes, int n_in,
                              void* d_out, int out_size, void* d_ws, size_t ws_size,
                              hipStream_t stream) {
  const float* qf   = (const float*)d_in[0];
  const float* kf   = (const float*)d_in[1];
  const float* qpos = (const float*)d_in[2];
  const float* kpos = (const float*)d_in[3];
  const float* Wq   = (const float*)d_in[4];
  const float* bq   = (const float*)d_in[5];
  const float* Wk   = (const float*)d_in[6];
  const float* bk   = (const float*)d_in[7];
  const float* Wv   = (const float*)d_in[8];
  const float* bv   = (const float*)d_in[9];
  const float* W1   = (const float*)d_in[10];
  const float* b1   = (const float*)d_in[11];
  const float* W2   = (const float*)d_in[12];
  const float* b2   = (const float*)d_in[13];
  float* ws  = (float*)d_ws;
  float* out = (float*)d_out;

  k_prep<<<128, 128, 0, stream>>>(Wq, bq, Wk, bk, Wv, W2, b2, ws);
  k_rowsums<<<1024, 256, 0, stream>>>(kf, qf, kpos, ws);
  k_knn<<<1024, 256, 0, stream>>>(qpos, kpos, W1, b1, ws);
  k_gather<<<1024, 256, 0, stream>>>(kf, ws);
  k_out<<<256, 256, 0, stream>>>(bv, ws, out);
}

// Round 7
// 182.313 us; speedup vs baseline: 1.8584x; 1.1224x over previous
//
#include <hip/hip_runtime.h>
#include <hip/hip_bf16.h>

#define BB 4
#define SS 1024
#define NPTS 16384
#define DD 128
#define EPSF 1e-6f

// ws layout (float element offsets), total ~2.99 MB
#define OFF_CQ     0        // 128  colsum(Wq)
#define OFF_CK     128      // 128  colsum(Wk)
#define OFF_W2S    256      // 128  colsum(W2)
#define OFF_SCL    384      // 8    [0]=sum(bq) [1]=sum(bk) [2]=sum(b2)
#define OFF_COL    448      // 64   colsum of attn over S, per (b,j)
#define OFF_QSUM   512      // 4096
#define OFF_KSUM   4608     // 65536
#define OFF_IDX    70144    // 65536 (int)
#define OFF_ATTN   135680   // 65536
#define OFF_ASUM   201216   // 4096
#define OFF_G      205312   // 524288 (k_gather output; during k_knn reused as kp4: (x,y,z,kk) per point, 262144 floats)
#define OFF_WVT    729600   // 16384 (Wv transposed)

__device__ __forceinline__ unsigned long long shflxor_u64(unsigned long long v, int m) {
  unsigned int lo = (unsigned int)(v & 0xffffffffull);
  unsigned int hi = (unsigned int)(v >> 32);
  lo = (unsigned int)__shfl_xor((int)lo, m, 64);
  hi = (unsigned int)__shfl_xor((int)hi, m, 64);
  return ((unsigned long long)hi << 32) | (unsigned long long)lo;
}

__device__ __forceinline__ unsigned long long u64min(unsigned long long a, unsigned long long b) {
  return a < b ? a : b;
}

__device__ __forceinline__ unsigned long long wavemin_u64(unsigned long long v) {
#pragma unroll
  for (int m = 1; m <= 32; m <<= 1) v = u64min(v, shflxor_u64(v, m));
  return v;
}

// ---------- K1: column sums, bias sums, Wv transpose, zero colsum ----------
// 128 blocks x 128 threads: block j = output column j
__global__ __launch_bounds__(128) void k_prep(const float* __restrict__ Wq, const float* __restrict__ bq,
                       const float* __restrict__ Wk, const float* __restrict__ bk,
                       const float* __restrict__ Wv, const float* __restrict__ W2,
                       const float* __restrict__ b2, float* __restrict__ ws) {
  const int j = (int)blockIdx.x;
  const int t = threadIdx.x;
  __shared__ float pr[6];
  __shared__ float pb[6];
  float s0 = Wq[t * DD + j], s1 = Wk[t * DD + j], s2 = W2[t * DD + j];
#pragma unroll
  for (int m = 1; m <= 32; m <<= 1) {
    s0 += __shfl_xor(s0, m, 64);
    s1 += __shfl_xor(s1, m, 64);
    s2 += __shfl_xor(s2, m, 64);
  }
  if ((t & 63) == 0) { const int wv = t >> 6; pr[wv*3+0]=s0; pr[wv*3+1]=s1; pr[wv*3+2]=s2; }
  __syncthreads();
  if (t == 0) {
    ws[OFF_CQ + j]  = pr[0] + pr[3];
    ws[OFF_CK + j]  = pr[1] + pr[4];
    ws[OFF_W2S + j] = pr[2] + pr[5];
  }
  ws[OFF_WVT + j * DD + t] = Wv[t * DD + j];
  if (j == 1 && t < 64) ws[OFF_COL + t] = 0.f;
  if (j == 0) {
    float a0 = bq[t], a1 = bk[t], a2 = b2[t];
#pragma unroll
    for (int m = 1; m <= 32; m <<= 1) {
      a0 += __shfl_xor(a0, m, 64);
      a1 += __shfl_xor(a1, m, 64);
      a2 += __shfl_xor(a2, m, 64);
    }
    if ((t & 63) == 0) { const int wv = t >> 6; pb[wv*3+0]=a0; pb[wv*3+1]=a1; pb[wv*3+2]=a2; }
    __syncthreads();
    if (t == 0) {
      ws[OFF_SCL + 0] = pb[0] + pb[3];
      ws[OFF_SCL + 1] = pb[1] + pb[4];
      ws[OFF_SCL + 2] = pb[2] + pb[5];
    }
  }
}

// ---------- K2: ksum/qsum row sums + pack kp4 = (x,y,z,kk) ----------
__global__ __launch_bounds__(256) void k_rowsums(const float* __restrict__ kf,
                                                 const float* __restrict__ qf,
                                                 const float* __restrict__ kpos,
                                                 float* __restrict__ ws) {
  const int tid = threadIdx.x;
  // pack kp4: first 65536 global threads each pack one point.
  // kk arithmetic identical to the original inline version: ((x*x + y*y) + z*z)
  const int pid = (int)blockIdx.x * 256 + tid;
  if (pid < BB * NPTS) {
    const float x = kpos[pid * 3 + 0], y = kpos[pid * 3 + 1], z = kpos[pid * 3 + 2];
    const float kk = __fadd_rn(__fadd_rn(__fmul_rn(x, x), __fmul_rn(y, y)), __fmul_rn(z, z));
    ((float4*)(ws + OFF_G))[pid] = make_float4(x, y, z, kk);
  }
  const int g = ((int)blockIdx.x * 256 + tid) >> 4;
  const int gl = tid & 15;
  const int ngroups = (int)gridDim.x * 16;
  const float bqs = ws[OFF_SCL + 0], bks = ws[OFF_SCL + 1];
  const int total = BB * NPTS + BB * SS;
  for (int row = g; row < total; row += ngroups) {
    const float* x;
    const float* c;
    if (row < BB * NPTS) { x = kf + (size_t)row * DD; c = ws + OFF_CK; }
    else                 { x = qf + (size_t)(row - BB * NPTS) * DD; c = ws + OFF_CQ; }
    float4 a  = *(const float4*)(x + gl * 4);
    float4 b  = *(const float4*)(x + 64 + gl * 4);
    float4 ca = *(const float4*)(c + gl * 4);
    float4 cb = *(const float4*)(c + 64 + gl * 4);
    float s = a.x * ca.x + a.y * ca.y + a.z * ca.z + a.w * ca.w
            + b.x * cb.x + b.y * cb.y + b.z * cb.z + b.w * cb.w;
    s += __shfl_xor(s, 1, 64);
    s += __shfl_xor(s, 2, 64);
    s += __shfl_xor(s, 4, 64);
    s += __shfl_xor(s, 8, 64);
    if (gl == 0) {
      if (row < BB * NPTS) ws[OFF_KSUM + row] = s + bks;
      else                 ws[OFF_QSUM + (row - BB * NPTS)] = s + bqs;
    }
  }
}

// ---------- K3: fused KNN + pe-sum + scores + softmax + colsum atomics ----------
// R7: Q=8 queries per block (512 thr, 8 waves; wave w scans slice w of 2048
// pts with the depth-4 register pipeline). Three changes vs R6, each against
// a measured cost:
//  (1) Q=8 halves L2 traffic / load instrs again (R6 still ~50% non-VALU).
//  (2) approx-fma d2 in both scan loops (5 ops vs 9); cutoff carries a +2e-5
//      margin (>= 2x the 8-ulp |d2a-d2e| bound for d2<=6), and the EXACT
//      descending-order d2 is computed only inside the pred branch (~50
//      points/query) and used as the merge key -> selection bit-identical.
//  (3) O(1) cutoff: max over 16 groups of (min over that group's 1024
//      disjoint points). Each group-min is a distinct point's d2 => >=16
//      distinct points <= cutoff => cutoff >= true 16th distance. 6 chained
//      shfl per query vs 96 (R6's 16-round knockout was ~12k latency cycles).
//      Looser cutoff => ~53 cands/query (~7 per slice, cap 64, P(ovfl)~0).
//  merge: wave qi merges query qi's 8 buffers (cand[8]/lane, 16-round
//  wave-min mark-and-rescan over exact (d2,idx) u64 keys) -> identical
//  ascending top-16; epilogue (pe/softmax/colsum) unchanged.
// d2 key matches numpy's einsum C kernel bit-for-bit (verified R8):
//   dot: DESCENDING no-FMA; qq/kk: plain squares, ASCENDING add;
//   d2 = (qq - 2*dot) + kk. kk precomputed in k_rowsums with same ops.
#define FORQ(X) X(0) X(1) X(2) X(3) X(4) X(5) X(6) X(7)

__global__ __launch_bounds__(512, 4) void k_knn(const float* __restrict__ qpos,
                                                const float* __restrict__ kpos,
                                                const float* __restrict__ W1,
                                                const float* __restrict__ b1,
                                                float* __restrict__ ws) {
  __shared__ unsigned long long cbuf[8][8][64];  // [query][wave][slot] 32 KB
  __shared__ float pmins[8][8][64];              // [wave][query][lane] 16 KB
  __shared__ int cnts[8][8];                     // [query][wave]
  const int tid = threadIdx.x;
  const int w = tid >> 6, l = tid & 63;
  const int qbase = (int)blockIdx.x * 8;
  const int b = qbase >> 10;   // 1024 % 8 == 0: all 8 queries in same batch

  const float4* kp4 = (const float4*)(ws + OFF_G) + (size_t)b * NPTS;
  const float* kp = kpos + (size_t)b * NPTS * 3;

#define LOADQ(i) \
  const float qx##i = qpos[(size_t)(qbase + i) * 3 + 0]; \
  const float qy##i = qpos[(size_t)(qbase + i) * 3 + 1]; \
  const float qz##i = qpos[(size_t)(qbase + i) * 3 + 2]; \
  const float qq##i = __fadd_rn(__fadd_rn(__fmul_rn(qx##i, qx##i), __fmul_rn(qy##i, qy##i)), __fmul_rn(qz##i, qz##i));
  FORQ(LOADQ)
#undef LOADQ

  const int sbase = w * 2048;

  // ---- pass 1: per-lane min of approx-fma d2, 8 queries per loaded point ----
  // Final-iteration prefetch reads up to ~256 float4 past the slice; for
  // wave 7 of batch 3 that lands in ws slack below OFF_WVT. Discarded.
#define DECLMN(i) float mn##i = 3.4e38f;
  FORQ(DECLMN)
#undef DECLMN
  {
    const float4* p0 = kp4 + sbase + l;
    float4 c0 = p0[0], c1 = p0[64], c2 = p0[128], c3 = p0[192];
    const float4* nx = p0 + 256;
#define P1Q(i, cc) { \
      const float dA = fmaf(qx##i, (cc).x, fmaf(qy##i, (cc).y, __fmul_rn(qz##i, (cc).z))); \
      const float d2a = __fadd_rn(fmaf(-2.0f, dA, qq##i), (cc).w); \
      mn##i = fminf(mn##i, d2a); }
#define P1_PT(cc, RELOAD) { \
      P1Q(0, cc) P1Q(1, cc) P1Q(2, cc) P1Q(3, cc) \
      P1Q(4, cc) P1Q(5, cc) P1Q(6, cc) P1Q(7, cc) \
      cc = RELOAD; }
    for (int t = 0; t < 8; ++t) {
      P1_PT(c0, nx[0])
      P1_PT(c1, nx[64])
      P1_PT(c2, nx[128])
      P1_PT(c3, nx[192])
      nx += 256;
    }
#undef P1_PT
  }
#define STMN(i) pmins[w][i][l] = mn##i;
  FORQ(STMN)
#undef STMN
  __syncthreads();

  // ---- cutoffs: per query, max over 16 groups of min-over-1024-points ----
  // lane-min (per wave) covers 32 disjoint points; min over 8 waves + lanes
  // {l, l+16, l+32, l+48} covers 1024; groups g = l&15 partition all 16384.
  // Each group-min is one distinct point's approx d2; max over the 16 groups
  // bounds the true 16th distance (+margin covers approx-vs-exact rounding).
#define CUTQ(i) float cut##i; { \
    float m = pmins[0][i][l]; \
    m = fminf(m, pmins[1][i][l]); m = fminf(m, pmins[2][i][l]); \
    m = fminf(m, pmins[3][i][l]); m = fminf(m, pmins[4][i][l]); \
    m = fminf(m, pmins[5][i][l]); m = fminf(m, pmins[6][i][l]); \
    m = fminf(m, pmins[7][i][l]); \
    m = fminf(m, __shfl_xor(m, 16, 64)); \
    m = fminf(m, __shfl_xor(m, 32, 64)); \
    m = fmaxf(m, __shfl_xor(m, 1, 64)); \
    m = fmaxf(m, __shfl_xor(m, 2, 64)); \
    m = fmaxf(m, __shfl_xor(m, 4, 64)); \
    m = fmaxf(m, __shfl_xor(m, 8, 64)); \
    cut##i = m + 2e-5f; }
  FORQ(CUTQ)
#undef CUTQ

  // ---- pass 2: approx filter, exact d2 key for survivors, ballot-compact ----
#define DECLCNT(i) int cnt##i = 0;
  FORQ(DECLCNT)
#undef DECLCNT
  {
    const float4* p0 = kp4 + sbase + l;
    float4 c0 = p0[0], c1 = p0[64], c2 = p0[128], c3 = p0[192];
    const float4* nx = p0 + 256;
    int p = sbase + l;
#define P2Q(i, cc, pp) { \
      const float dA = fmaf(qx##i, (cc).x, fmaf(qy##i, (cc).y, __fmul_rn(qz##i, (cc).z))); \
      const float d2a = __fadd_rn(fmaf(-2.0f, dA, qq##i), (cc).w); \
      const bool pred = (d2a <= cut##i); \
      const unsigned long long mask = __ballot(pred); \
      if (mask) { \
        if (pred) { \
          const float dotE = __fadd_rn(__fadd_rn(__fmul_rn(qz##i, (cc).z), __fmul_rn(qy##i, (cc).y)), __fmul_rn(qx##i, (cc).x)); \
          const float d2e = __fadd_rn(__fsub_rn(qq##i, __fmul_rn(2.0f, dotE)), (cc).w); \
          unsigned int u = __float_as_uint(d2e); \
          u ^= (unsigned int)((int)u >> 31) | 0x80000000u; \
          const int off = __builtin_amdgcn_mbcnt_hi((unsigned int)(mask >> 32), \
                          __builtin_amdgcn_mbcnt_lo((unsigned int)mask, 0)); \
          const int pos = cnt##i + off; \
          if (pos < 64) cbuf[i][w][pos] = ((unsigned long long)u << 32) | (unsigned int)(pp); \
        } \
        cnt##i += (int)__popcll(mask); \
      } }
#define P2_PT(cc, RELOAD, POFF) { \
      P2Q(0, cc, p + POFF) P2Q(1, cc, p + POFF) P2Q(2, cc, p + POFF) P2Q(3, cc, p + POFF) \
      P2Q(4, cc, p + POFF) P2Q(5, cc, p + POFF) P2Q(6, cc, p + POFF) P2Q(7, cc, p + POFF) \
      cc = RELOAD; }
    for (int t = 0; t < 8; ++t) {
      P2_PT(c0, nx[0], 0)
      P2_PT(c1, nx[64], 64)
      P2_PT(c2, nx[128], 128)
      P2_PT(c3, nx[192], 192)
      nx += 256;
      p += 256;
    }
#undef P2_PT
#undef P2Q
  }
#define STCNT(i) if (l == 0) cnts[i][w] = (cnt##i > 64 ? 64 : cnt##i);
  FORQ(STCNT)
#undef STCNT
  __syncthreads();

  // ---- merge + epilogue: wave w owns query qbase + w ----
  const int qi = w;
  const int q = qbase + qi;
  unsigned long long cand[8];
#pragma unroll
  for (int i = 0; i < 8; ++i) {
    const int cn = cnts[qi][i];
    cand[i] = (l < cn) ? cbuf[qi][i][l] : ~0ull;
  }
  unsigned long long lmin = cand[0]; int lpos = 0;
#pragma unroll
  for (int i = 1; i < 8; ++i) { if (cand[i] < lmin) { lmin = cand[i]; lpos = i; } }
  unsigned long long sel64 = 0;
  for (int r = 0; r < 16; ++r) {
    const unsigned long long m = wavemin_u64(lmin);
    if (l == r) sel64 = m;
    if (lmin == m) {
#pragma unroll
      for (int i = 0; i < 8; ++i) cand[i] = (lpos == i) ? ~0ull : cand[i];
      lmin = cand[0]; lpos = 0;
#pragma unroll
      for (int i = 1; i < 8; ++i) { if (cand[i] < lmin) { lmin = cand[i]; lpos = i; } }
    }
  }
  const int myidx = (int)(sel64 & 0xffffffffull);
  if (l < 16) ((int*)(ws + OFF_IDX))[q * 16 + l] = myidx;

  // scores: j = l&15, 4 replicas each cover 32 of the 128 pe terms
  const float* qpw = qpos + (size_t)q * 3;
  const float gx = qpw[0], gy = qpw[1], gz = qpw[2];
  const int j = l & 15;
  const int pj = __shfl(myidx, j, 64);
  const float* kpj = kp + (size_t)pj * 3;
  const float rx = gx - kpj[0];
  const float ry = gy - kpj[1];
  const float rz = gz - kpj[2];
  float pe = 0.f;
  const int i0 = (l >> 4) * 32;
  for (int i = i0; i < i0 + 32; ++i) {
    float hh = fmaf(rx, W1[i * 3 + 0], fmaf(ry, W1[i * 3 + 1], fmaf(rz, W1[i * 3 + 2], b1[i])));
    hh = fmaxf(hh, 0.f);
    pe = fmaf(hh, ws[OFF_W2S + i], pe);
  }
  pe += __shfl_xor(pe, 16, 64);
  pe += __shfl_xor(pe, 32, 64);
  float score = ws[OFF_QSUM + q] - ws[OFF_KSUM + b * NPTS + pj] + pe + ws[OFF_SCL + 2];
  float mx = score;
  mx = fmaxf(mx, __shfl_xor(mx, 1, 64));
  mx = fmaxf(mx, __shfl_xor(mx, 2, 64));
  mx = fmaxf(mx, __shfl_xor(mx, 4, 64));
  mx = fmaxf(mx, __shfl_xor(mx, 8, 64));
  const float e = expf(score - mx);
  float se = e;
  se += __shfl_xor(se, 1, 64);
  se += __shfl_xor(se, 2, 64);
  se += __shfl_xor(se, 4, 64);
  se += __shfl_xor(se, 8, 64);
  const float attn = e / se;
  if (l < 16) {
    ws[OFF_ATTN + q * 16 + l] = attn;
    atomicAdd(&ws[OFF_COL + b * 16 + l], attn);
  }
}

// ---------- K4: normalize attn, gather-weight k_feat rows -> g, asum ----------
__global__ __launch_bounds__(256) void k_gather(const float* __restrict__ kf,
                                                float* __restrict__ ws) {
  const int tid = threadIdx.x;
  const int w = tid >> 6, l = tid & 63;
  const int q = (int)blockIdx.x * 4 + w;
  const int b = q >> 10;
  float a = 0.f;
  int pidx = 0;
  if (l < 16) {
    a = ws[OFF_ATTN + q * 16 + l] / (ws[OFF_COL + b * 16 + l] + EPSF);
    pidx = ((const int*)(ws + OFF_IDX))[q * 16 + l];
  }
  float asum = a;
  asum += __shfl_xor(asum, 1, 64);
  asum += __shfl_xor(asum, 2, 64);
  asum += __shfl_xor(asum, 4, 64);
  asum += __shfl_xor(asum, 8, 64);
  if (l == 0) ws[OFF_ASUM + q] = asum;
  const float* kb = kf + (size_t)b * NPTS * DD;
  float acc0 = 0.f, acc1 = 0.f;
#pragma unroll
  for (int jj = 0; jj < 16; ++jj) {
    const float aj = __shfl(a, jj, 64);
    const int pj = __shfl(pidx, jj, 64);
    const float* row = kb + (size_t)pj * DD;
    acc0 = fmaf(aj, row[l], acc0);
    acc1 = fmaf(aj, row[64 + l], acc1);
  }
  ws[OFF_G + (size_t)q * DD + l] = acc0;
  ws[OFF_G + (size_t)q * DD + 64 + l] = acc1;
}

// ---------- K5: out = g @ Wv^T + asum * bv ----------
__global__ __launch_bounds__(256) void k_out(const float* __restrict__ bv,
                                             const float* __restrict__ ws,
                                             float* __restrict__ out) {
  __shared__ float xg[16 * 128];
  __shared__ float as_s[16];
  const int tid = threadIdx.x;
  const int rbase = (int)blockIdx.x * 16;
  for (int e = tid; e < 16 * 128; e += 256) xg[e] = ws[OFF_G + (size_t)rbase * DD + e];
  if (tid < 16) as_s[tid] = ws[OFF_ASUM + rbase + tid];
  __syncthreads();
  const int o = tid & 127, rg = tid >> 7;
  const float bvo = bv[o];
  float acc[8];
#pragma unroll
  for (int r = 0; r < 8; ++r) acc[r] = as_s[rg * 8 + r] * bvo;
  for (int i = 0; i < DD; ++i) {
    const float wv = ws[OFF_WVT + i * DD + o];
#pragma unroll
    for (int r = 0; r < 8; ++r) acc[r] = fmaf(wv, xg[(rg * 8 + r) * 128 + i], acc[r]);
  }
#pragma unroll
  for (int r = 0; r < 8; ++r) out[(size_t)(rbase + rg * 8 + r) * DD + o] = acc[r];
}

extern "C" void kernel_launch(void* const* d_in, const int* in_sizes, int n_in,
                              void* d_out, int out_size, void* d_ws, size_t ws_size,
                              hipStream_t stream) {
  const float* qf   = (const float*)d_in[0];
  const float* kf   = (const float*)d_in[1];
  const float* qpos = (const float*)d_in[2];
  const float* kpos = (const float*)d_in[3];
  const float* Wq   = (const float*)d_in[4];
  const float* bq   = (const float*)d_in[5];
  const float* Wk   = (const float*)d_in[6];
  const float* bk   = (const float*)d_in[7];
  const float* Wv   = (const float*)d_in[8];
  const float* bv   = (const float*)d_in[9];
  const float* W1   = (const float*)d_in[10];
  const float* b1   = (const float*)d_in[11];
  const float* W2   = (const float*)d_in[12];
  const float* b2   = (const float*)d_in[13];
  float* ws  = (float*)d_ws;
  float* out = (float*)d_out;

  k_prep<<<128, 128, 0, stream>>>(Wq, bq, Wk, bk, Wv, W2, b2, ws);
  k_rowsums<<<1024, 256, 0, stream>>>(kf, qf, kpos, ws);
  k_knn<<<512, 512, 0, stream>>>(qpos, kpos, W1, b1, ws);
  k_gather<<<1024, 256, 0, stream>>>(kf, ws);
  k_out<<<256, 256, 0, stream>>>(bv, ws, out);
}

// Round 8
// 173.099 us; speedup vs baseline: 1.9573x; 1.0532x over previous
//
#include <hip/hip_runtime.h>
#include <hip/hip_bf16.h>

#define BB 4
#define SS 1024
#define NPTS 16384
#define DD 128
#define EPSF 1e-6f

// ws layout (float element offsets), total ~2.99 MB
#define OFF_CQ     0        // 128  (unused after R8 fusion)
#define OFF_CK     128      // 128  (unused after R8 fusion)
#define OFF_W2S    256      // 128  colsum(W2)
#define OFF_SCL    384      // 8    [2]=sum(b2)
#define OFF_COL    448      // 64   colsum of attn over S, per (b,j)
#define OFF_QSUM   512      // 4096
#define OFF_KSUM   4608     // 65536
#define OFF_IDX    70144    // 65536 (int)
#define OFF_ATTN   135680   // 65536
#define OFF_ASUM   201216   // 4096 (unused after R8 fusion)
#define OFF_G      205312   // 524288 (kp4: (x,y,z,kk) per point, 262144 floats)
#define OFF_WVT    729600   // 16384 (Wv transposed)

__device__ __forceinline__ unsigned long long shflxor_u64(unsigned long long v, int m) {
  unsigned int lo = (unsigned int)(v & 0xffffffffull);
  unsigned int hi = (unsigned int)(v >> 32);
  lo = (unsigned int)__shfl_xor((int)lo, m, 64);
  hi = (unsigned int)__shfl_xor((int)hi, m, 64);
  return ((unsigned long long)hi << 32) | (unsigned long long)lo;
}

__device__ __forceinline__ unsigned long long u64min(unsigned long long a, unsigned long long b) {
  return a < b ? a : b;
}

__device__ __forceinline__ unsigned long long wavemin_u64(unsigned long long v) {
#pragma unroll
  for (int m = 1; m <= 32; m <<= 1) v = u64min(v, shflxor_u64(v, m));
  return v;
}

// ---------- K1: fused prep + rowsums + kp4 pack ----------
// 1024 blocks x 256. Every block computes colsum(Wq)/colsum(Wk) + bias sums
// REDUNDANTLY (Wq/Wk are L2-resident, 128KB/block) -> no producer kernel.
// Designated blocks: 0..127 write WVT col j=bid (as old k_prep); 128 zeroes
// COL; 256 computes W2S + SCL2. First 256 blocks pack kp4 (identical FP ops
// to the harness-verified version). Then all blocks run the row-sum loop
// (ksum/qsum) reading colsums from LDS.
__global__ __launch_bounds__(256) void k_pre(const float* __restrict__ kf,
                                             const float* __restrict__ qf,
                                             const float* __restrict__ kpos,
                                             const float* __restrict__ Wq,
                                             const float* __restrict__ bq,
                                             const float* __restrict__ Wk,
                                             const float* __restrict__ bk,
                                             const float* __restrict__ Wv,
                                             const float* __restrict__ W2,
                                             const float* __restrict__ b2,
                                             float* __restrict__ ws) {
  const int tid = threadIdx.x;
  const int bid = (int)blockIdx.x;
  __shared__ __align__(16) float cq_s[128];
  __shared__ __align__(16) float ck_s[128];
  __shared__ float part[256];
  __shared__ float scl_s[2];

  // --- per-block colsums of Wq, Wk ---
  {
    const int j = tid & 127, h = tid >> 7;
    const int r0 = h * 64;
    float sq = 0.f, sk = 0.f;
    for (int r = r0; r < r0 + 64; ++r) {
      sq += Wq[r * DD + j];
      sk += Wk[r * DD + j];
    }
    part[tid] = sq;
    __syncthreads();
    if (h == 0) cq_s[j] = part[j] + part[128 + j];
    __syncthreads();
    part[tid] = sk;
    __syncthreads();
    if (h == 0) ck_s[j] = part[j] + part[128 + j];
  }
  // --- bias sums (local) ---
  if (tid < 64) {
    float a0 = bq[tid] + bq[tid + 64];
    float a1 = bk[tid] + bk[tid + 64];
#pragma unroll
    for (int m = 1; m <= 32; m <<= 1) {
      a0 += __shfl_xor(a0, m, 64);
      a1 += __shfl_xor(a1, m, 64);
    }
    if (tid == 0) { scl_s[0] = a0; scl_s[1] = a1; }
  }

  // --- designated-block extras ---
  if (bid < 128) {
    if (tid < 128) ws[OFF_WVT + bid * DD + tid] = Wv[tid * DD + bid];
  } else if (bid == 128) {
    if (tid < 64) ws[OFF_COL + tid] = 0.f;
  } else if (bid == 256) {
    const int j = tid & 127, h = tid >> 7;
    const int r0 = h * 64;
    float s2 = 0.f;
    for (int r = r0; r < r0 + 64; ++r) s2 += W2[r * DD + j];
    __syncthreads();
    part[tid] = s2;
    __syncthreads();
    if (h == 0) ws[OFF_W2S + j] = part[j] + part[128 + j];
    if (tid < 64) {
      float a2 = b2[tid] + b2[tid + 64];
#pragma unroll
      for (int m = 1; m <= 32; m <<= 1) a2 += __shfl_xor(a2, m, 64);
      if (tid == 0) ws[OFF_SCL + 2] = a2;
    }
  }

  // --- pack kp4 (blocks 0..255; identical FP ops to verified version) ---
  const int pid = bid * 256 + tid;
  if (pid < BB * NPTS) {
    const float x = kpos[pid * 3 + 0], y = kpos[pid * 3 + 1], z = kpos[pid * 3 + 2];
    const float kk = __fadd_rn(__fadd_rn(__fmul_rn(x, x), __fmul_rn(y, y)), __fmul_rn(z, z));
    ((float4*)(ws + OFF_G))[pid] = make_float4(x, y, z, kk);
  }
  __syncthreads();
  const float bqs = scl_s[0], bks = scl_s[1];

  // --- row sums: ksum (65536 rows) + qsum (4096 rows) ---
  const int g = (bid * 256 + tid) >> 4;
  const int gl = tid & 15;
  const int ngroups = (int)gridDim.x * 16;
  const int total = BB * NPTS + BB * SS;
  for (int row = g; row < total; row += ngroups) {
    const float* x;
    const float* c;
    if (row < BB * NPTS) { x = kf + (size_t)row * DD; c = ck_s; }
    else                 { x = qf + (size_t)(row - BB * NPTS) * DD; c = cq_s; }
    float4 a  = *(const float4*)(x + gl * 4);
    float4 b  = *(const float4*)(x + 64 + gl * 4);
    float4 ca = *(const float4*)(c + gl * 4);
    float4 cb = *(const float4*)(c + 64 + gl * 4);
    float s = a.x * ca.x + a.y * ca.y + a.z * ca.z + a.w * ca.w
            + b.x * cb.x + b.y * cb.y + b.z * cb.z + b.w * cb.w;
    s += __shfl_xor(s, 1, 64);
    s += __shfl_xor(s, 2, 64);
    s += __shfl_xor(s, 4, 64);
    s += __shfl_xor(s, 8, 64);
    if (gl == 0) {
      if (row < BB * NPTS) ws[OFF_KSUM + row] = s + bks;
      else                 ws[OFF_QSUM + (row - BB * NPTS)] = s + bqs;
    }
  }
}

// ---------- K2: fused KNN + pe-sum + scores + softmax + colsum atomics ----------
// R8 = R7's verified structure + XCD-aware block swizzle (bid&7 -> batch) so
// each XCD's resident blocks share one batch's 1MB kp4 -> pass-2 re-reads hit
// that XCD's L2 (FETCH_SIZE down, scan latency down). Pure block remap;
// every query still processed exactly once; selection logic unchanged.
// d2 key matches numpy's einsum C kernel bit-for-bit (verified R8):
//   dot: DESCENDING no-FMA; qq/kk: plain squares, ASCENDING add;
//   d2 = (qq - 2*dot) + kk. kk precomputed in k_pre with same ops.
#define FORQ(X) X(0) X(1) X(2) X(3) X(4) X(5) X(6) X(7)

__global__ __launch_bounds__(512, 4) void k_knn(const float* __restrict__ qpos,
                                                const float* __restrict__ kpos,
                                                const float* __restrict__ W1,
                                                const float* __restrict__ b1,
                                                float* __restrict__ ws) {
  __shared__ unsigned long long cbuf[8][8][64];  // [query][wave][slot] 32 KB
  __shared__ float pmins[8][8][64];              // [wave][query][lane] 16 KB
  __shared__ int cnts[8][8];                     // [query][wave]
  const int tid = threadIdx.x;
  const int w = tid >> 6, l = tid & 63;
  // XCD swizzle: batch = xcd&3 so all blocks on one XCD scan the same batch.
  const int bid = (int)blockIdx.x;
  const int xcd = bid & 7, s = bid >> 3;
  const int batch = xcd & 3;
  const int idx = ((xcd >> 2) << 6) + s;   // 0..127, bijective per batch
  const int qbase = batch * 1024 + idx * 8;
  const int b = batch;

  const float4* kp4 = (const float4*)(ws + OFF_G) + (size_t)b * NPTS;
  const float* kp = kpos + (size_t)b * NPTS * 3;

#define LOADQ(i) \
  const float qx##i = qpos[(size_t)(qbase + i) * 3 + 0]; \
  const float qy##i = qpos[(size_t)(qbase + i) * 3 + 1]; \
  const float qz##i = qpos[(size_t)(qbase + i) * 3 + 2]; \
  const float qq##i = __fadd_rn(__fadd_rn(__fmul_rn(qx##i, qx##i), __fmul_rn(qy##i, qy##i)), __fmul_rn(qz##i, qz##i));
  FORQ(LOADQ)
#undef LOADQ

  const int sbase = w * 2048;

  // ---- pass 1: per-lane min of approx-fma d2, 8 queries per loaded point ----
#define DECLMN(i) float mn##i = 3.4e38f;
  FORQ(DECLMN)
#undef DECLMN
  {
    const float4* p0 = kp4 + sbase + l;
    float4 c0 = p0[0], c1 = p0[64], c2 = p0[128], c3 = p0[192];
    const float4* nx = p0 + 256;
#define P1Q(i, cc) { \
      const float dA = fmaf(qx##i, (cc).x, fmaf(qy##i, (cc).y, __fmul_rn(qz##i, (cc).z))); \
      const float d2a = __fadd_rn(fmaf(-2.0f, dA, qq##i), (cc).w); \
      mn##i = fminf(mn##i, d2a); }
#define P1_PT(cc, RELOAD) { \
      P1Q(0, cc) P1Q(1, cc) P1Q(2, cc) P1Q(3, cc) \
      P1Q(4, cc) P1Q(5, cc) P1Q(6, cc) P1Q(7, cc) \
      cc = RELOAD; }
    for (int t = 0; t < 8; ++t) {
      P1_PT(c0, nx[0])
      P1_PT(c1, nx[64])
      P1_PT(c2, nx[128])
      P1_PT(c3, nx[192])
      nx += 256;
    }
#undef P1_PT
  }
#define STMN(i) pmins[w][i][l] = mn##i;
  FORQ(STMN)
#undef STMN
  __syncthreads();

  // ---- cutoffs: per query, max over 16 groups of min-over-1024-points ----
#define CUTQ(i) float cut##i; { \
    float m = pmins[0][i][l]; \
    m = fminf(m, pmins[1][i][l]); m = fminf(m, pmins[2][i][l]); \
    m = fminf(m, pmins[3][i][l]); m = fminf(m, pmins[4][i][l]); \
    m = fminf(m, pmins[5][i][l]); m = fminf(m, pmins[6][i][l]); \
    m = fminf(m, pmins[7][i][l]); \
    m = fminf(m, __shfl_xor(m, 16, 64)); \
    m = fminf(m, __shfl_xor(m, 32, 64)); \
    m = fmaxf(m, __shfl_xor(m, 1, 64)); \
    m = fmaxf(m, __shfl_xor(m, 2, 64)); \
    m = fmaxf(m, __shfl_xor(m, 4, 64)); \
    m = fmaxf(m, __shfl_xor(m, 8, 64)); \
    cut##i = m + 2e-5f; }
  FORQ(CUTQ)
#undef CUTQ

  // ---- pass 2: approx filter, exact d2 key for survivors, ballot-compact ----
#define DECLCNT(i) int cnt##i = 0;
  FORQ(DECLCNT)
#undef DECLCNT
  {
    const float4* p0 = kp4 + sbase + l;
    float4 c0 = p0[0], c1 = p0[64], c2 = p0[128], c3 = p0[192];
    const float4* nx = p0 + 256;
    int p = sbase + l;
#define P2Q(i, cc, pp) { \
      const float dA = fmaf(qx##i, (cc).x, fmaf(qy##i, (cc).y, __fmul_rn(qz##i, (cc).z))); \
      const float d2a = __fadd_rn(fmaf(-2.0f, dA, qq##i), (cc).w); \
      const bool pred = (d2a <= cut##i); \
      const unsigned long long mask = __ballot(pred); \
      if (mask) { \
        if (pred) { \
          const float dotE = __fadd_rn(__fadd_rn(__fmul_rn(qz##i, (cc).z), __fmul_rn(qy##i, (cc).y)), __fmul_rn(qx##i, (cc).x)); \
          const float d2e = __fadd_rn(__fsub_rn(qq##i, __fmul_rn(2.0f, dotE)), (cc).w); \
          unsigned int u = __float_as_uint(d2e); \
          u ^= (unsigned int)((int)u >> 31) | 0x80000000u; \
          const int off = __builtin_amdgcn_mbcnt_hi((unsigned int)(mask >> 32), \
                          __builtin_amdgcn_mbcnt_lo((unsigned int)mask, 0)); \
          const int pos = cnt##i + off; \
          if (pos < 64) cbuf[i][w][pos] = ((unsigned long long)u << 32) | (unsigned int)(pp); \
        } \
        cnt##i += (int)__popcll(mask); \
      } }
#define P2_PT(cc, RELOAD, POFF) { \
      P2Q(0, cc, p + POFF) P2Q(1, cc, p + POFF) P2Q(2, cc, p + POFF) P2Q(3, cc, p + POFF) \
      P2Q(4, cc, p + POFF) P2Q(5, cc, p + POFF) P2Q(6, cc, p + POFF) P2Q(7, cc, p + POFF) \
      cc = RELOAD; }
    for (int t = 0; t < 8; ++t) {
      P2_PT(c0, nx[0], 0)
      P2_PT(c1, nx[64], 64)
      P2_PT(c2, nx[128], 128)
      P2_PT(c3, nx[192], 192)
      nx += 256;
      p += 256;
    }
#undef P2_PT
#undef P2Q
  }
#define STCNT(i) if (l == 0) cnts[i][w] = (cnt##i > 64 ? 64 : cnt##i);
  FORQ(STCNT)
#undef STCNT
  __syncthreads();

  // ---- merge + epilogue: wave w owns query qbase + w ----
  const int qi = w;
  const int q = qbase + qi;
  unsigned long long cand[8];
#pragma unroll
  for (int i = 0; i < 8; ++i) {
    const int cn = cnts[qi][i];
    cand[i] = (l < cn) ? cbuf[qi][i][l] : ~0ull;
  }
  unsigned long long lmin = cand[0]; int lpos = 0;
#pragma unroll
  for (int i = 1; i < 8; ++i) { if (cand[i] < lmin) { lmin = cand[i]; lpos = i; } }
  unsigned long long sel64 = 0;
  for (int r = 0; r < 16; ++r) {
    const unsigned long long m = wavemin_u64(lmin);
    if (l == r) sel64 = m;
    if (lmin == m) {
#pragma unroll
      for (int i = 0; i < 8; ++i) cand[i] = (lpos == i) ? ~0ull : cand[i];
      lmin = cand[0]; lpos = 0;
#pragma unroll
      for (int i = 1; i < 8; ++i) { if (cand[i] < lmin) { lmin = cand[i]; lpos = i; } }
    }
  }
  const int myidx = (int)(sel64 & 0xffffffffull);
  if (l < 16) ((int*)(ws + OFF_IDX))[q * 16 + l] = myidx;

  // scores: j = l&15, 4 replicas each cover 32 of the 128 pe terms
  const float* qpw = qpos + (size_t)q * 3;
  const float gx = qpw[0], gy = qpw[1], gz = qpw[2];
  const int j = l & 15;
  const int pj = __shfl(myidx, j, 64);
  const float* kpj = kp + (size_t)pj * 3;
  const float rx = gx - kpj[0];
  const float ry = gy - kpj[1];
  const float rz = gz - kpj[2];
  float pe = 0.f;
  const int i0 = (l >> 4) * 32;
  for (int i = i0; i < i0 + 32; ++i) {
    float hh = fmaf(rx, W1[i * 3 + 0], fmaf(ry, W1[i * 3 + 1], fmaf(rz, W1[i * 3 + 2], b1[i])));
    hh = fmaxf(hh, 0.f);
    pe = fmaf(hh, ws[OFF_W2S + i], pe);
  }
  pe += __shfl_xor(pe, 16, 64);
  pe += __shfl_xor(pe, 32, 64);
  float score = ws[OFF_QSUM + q] - ws[OFF_KSUM + b * NPTS + pj] + pe + ws[OFF_SCL + 2];
  float mx = score;
  mx = fmaxf(mx, __shfl_xor(mx, 1, 64));
  mx = fmaxf(mx, __shfl_xor(mx, 2, 64));
  mx = fmaxf(mx, __shfl_xor(mx, 4, 64));
  mx = fmaxf(mx, __shfl_xor(mx, 8, 64));
  const float e = expf(score - mx);
  float se = e;
  se += __shfl_xor(se, 1, 64);
  se += __shfl_xor(se, 2, 64);
  se += __shfl_xor(se, 4, 64);
  se += __shfl_xor(se, 8, 64);
  const float attn = e / se;
  if (l < 16) {
    ws[OFF_ATTN + q * 16 + l] = attn;
    atomicAdd(&ws[OFF_COL + b * 16 + l], attn);
  }
}

// ---------- K3: fused gather + out ----------
// 512 blocks x 256 (4 waves). Block owns 8 queries; wave w gathers queries
// w*2, w*2+1 (normalize attn, asum, 16-row weighted sum of kf) into LDS xg,
// then all threads compute out = xg @ Wv^T + asum*bv (o = tid&127, row-group
// rg = tid>>7 covers 4 rows). FP order of both phases identical to the
// previous k_gather/k_out (init asum*bvo, ascending-i fmaf).
__global__ __launch_bounds__(256) void k_go(const float* __restrict__ kf,
                                            const float* __restrict__ bv,
                                            const float* __restrict__ ws,
                                            float* __restrict__ out) {
  __shared__ float xg[8 * 128];
  __shared__ float as_s[8];
  const int tid = threadIdx.x;
  const int w = tid >> 6, l = tid & 63;
  const int qbase = (int)blockIdx.x * 8;
  const int b = qbase >> 10;
  const float* kb = kf + (size_t)b * NPTS * DD;

#pragma unroll
  for (int u = 0; u < 2; ++u) {
    const int qi = w * 2 + u;
    const int q = qbase + qi;
    float a = 0.f;
    int pidx = 0;
    if (l < 16) {
      a = ws[OFF_ATTN + q * 16 + l] / (ws[OFF_COL + b * 16 + l] + EPSF);
      pidx = ((const int*)(ws + OFF_IDX))[q * 16 + l];
    }
    float asum = a;
    asum += __shfl_xor(asum, 1, 64);
    asum += __shfl_xor(asum, 2, 64);
    asum += __shfl_xor(asum, 4, 64);
    asum += __shfl_xor(asum, 8, 64);
    if (l == 0) as_s[qi] = asum;
    float acc0 = 0.f, acc1 = 0.f;
#pragma unroll
    for (int jj = 0; jj < 16; ++jj) {
      const float aj = __shfl(a, jj, 64);
      const int pj = __shfl(pidx, jj, 64);
      const float* row = kb + (size_t)pj * DD;
      acc0 = fmaf(aj, row[l], acc0);
      acc1 = fmaf(aj, row[64 + l], acc1);
    }
    xg[qi * 128 + l] = acc0;
    xg[qi * 128 + 64 + l] = acc1;
  }
  __syncthreads();

  const int o = tid & 127, rg = tid >> 7;  // rg 0..1, rows rg*4 .. rg*4+3
  const float bvo = bv[o];
  float acc[4];
#pragma unroll
  for (int r = 0; r < 4; ++r) acc[r] = as_s[rg * 4 + r] * bvo;
  for (int i = 0; i < DD; ++i) {
    const float wv = ws[OFF_WVT + i * DD + o];
#pragma unroll
    for (int r = 0; r < 4; ++r) acc[r] = fmaf(wv, xg[(rg * 4 + r) * 128 + i], acc[r]);
  }
#pragma unroll
  for (int r = 0; r < 4; ++r) out[(size_t)(qbase + rg * 4 + r) * DD + o] = acc[r];
}

extern "C" void kernel_launch(void* const* d_in, const int* in_sizes, int n_in,
                              void* d_out, int out_size, void* d_ws, size_t ws_size,
                              hipStream_t stream) {
  const float* qf   = (const float*)d_in[0];
  const float* kf   = (const float*)d_in[1];
  const float* qpos = (const float*)d_in[2];
  const float* kpos = (const float*)d_in[3];
  const float* Wq   = (const float*)d_in[4];
  const float* bq   = (const float*)d_in[5];
  const float* Wk   = (const float*)d_in[6];
  const float* bk   = (const float*)d_in[7];
  const float* Wv   = (const float*)d_in[8];
  const float* bv   = (const float*)d_in[9];
  const float* W1   = (const float*)d_in[10];
  const float* b1   = (const float*)d_in[11];
  const float* W2   = (const float*)d_in[12];
  const float* b2   = (const float*)d_in[13];
  float* ws  = (float*)d_ws;
  float* out = (float*)d_out;

  k_pre<<<1024, 256, 0, stream>>>(kf, qf, kpos, Wq, bq, Wk, bk, Wv, W2, b2, ws);
  k_knn<<<512, 512, 0, stream>>>(qpos, kpos, W1, b1, ws);
  k_go<<<512, 256, 0, stream>>>(kf, bv, ws, out);
}